// Round 3
// baseline (801.824 us; speedup 1.0000x reference)
//
#include <hip/hip_runtime.h>

#define B_    4
#define T_    4096
#define D_    1024
#define H_    16
#define DH_   64
#define KTOK  2048
#define MROWS (B_*KTOK)   // 8192

typedef unsigned short u16;
typedef __attribute__((ext_vector_type(8))) short short8;
typedef __attribute__((ext_vector_type(4))) float f32x4;
typedef __attribute__((ext_vector_type(4))) unsigned int u32x4;
typedef __attribute__((ext_vector_type(2))) unsigned int u32x2;
typedef __attribute__((ext_vector_type(4))) unsigned short u16x4;

static __device__ __forceinline__ u16 f2bf(float f) {
  union { float f; unsigned int u; } a; a.f = f;
  unsigned int u = a.u;
  unsigned int r = (u + 0x7FFFu + ((u >> 16) & 1u)) >> 16;   // RNE
  return (u16)r;
}

#if defined(__has_builtin)
#if __has_builtin(__builtin_amdgcn_exp2f)
#define EXP2F(x) __builtin_amdgcn_exp2f(x)
#endif
#endif
#ifndef EXP2F
#define EXP2F(x) exp2f(x)
#endif

// pack two fp32 -> adjacent bf16 pair (low = a), TRUNCATING (1 v_perm).
static __device__ __forceinline__ unsigned int pkbf_t(float a, float b) {
  unsigned int ua = __builtin_bit_cast(unsigned int, a);
  unsigned int ub = __builtin_bit_cast(unsigned int, b);
  return __builtin_amdgcn_perm(ub, ua, 0x07060302u);  // [ua.hi16 low, ub.hi16 high]
}

static __device__ __forceinline__ void gld_lds16(const u16* g, u16* l) {
  __builtin_amdgcn_global_load_lds((__attribute__((address_space(1))) void*)g,
                                   (__attribute__((address_space(3))) void*)l, 16, 0, 0);
}

#define WAITV(N) asm volatile("s_waitcnt vmcnt(" #N ")" ::: "memory")

// ---------------- router: logits = x @ w_router, accumulate sum(logits^2) ----------------
__global__ void __launch_bounds__(256) router_kernel(const float* __restrict__ x,
    const float* __restrict__ wr, float* __restrict__ logits, float* __restrict__ auxacc)
{
  int tid = threadIdx.x; int lane = tid & 63, wave = tid >> 6;
  int row = blockIdx.x * 4 + wave;                 // 0 .. B*T-1
  const float* xr = x + (size_t)row * D_;
  float dot = 0.f;
#pragma unroll
  for (int j = 0; j < 4; j++) {
    int c = j * 256 + lane * 4;
    f32x4 xv = *(const f32x4*)(xr + c);
    f32x4 wv = *(const f32x4*)(wr + c);
    dot += xv[0]*wv[0] + xv[1]*wv[1] + xv[2]*wv[2] + xv[3]*wv[3];
  }
#pragma unroll
  for (int d = 1; d < 64; d <<= 1) dot += __shfl_xor(dot, d);
  __shared__ float red[4];
  if (lane == 0) { logits[row] = dot; red[wave] = dot; }
  __syncthreads();
  if (tid == 0) {
    float a = red[0]*red[0] + red[1]*red[1] + red[2]*red[2] + red[3]*red[3];
    atomicAdd(auxacc, a);
  }
}

// ---------------- rank: write RANK per token (rank<KTOK => selected, slot=rank) -----------
__global__ void __launch_bounds__(256) rank_kernel(const float* __restrict__ logits,
    int* __restrict__ rnk, int* __restrict__ idx,
    const float* __restrict__ acc, float* __restrict__ auxout)
{
  __shared__ float ll[T_];
  int b = blockIdx.y;
  int tid = threadIdx.x;
  if (b == 0 && blockIdx.x == 0 && tid == 0)
    auxout[0] = acc[0] * (0.01f / (float)(B_ * T_));
  const float* lg = logits + (size_t)b * T_;
  for (int j = tid; j < T_; j += 256) ll[j] = lg[j];
  __syncthreads();
  int t = blockIdx.x * 256 + tid;
  float my = ll[t];
  int rank = 0;
  for (int j = 0; j < T_; j += 4) {
    f32x4 lj = *(const f32x4*)&ll[j];
    rank += (lj[0] > my) || (lj[0] == my && (j+0) < t);
    rank += (lj[1] > my) || (lj[1] == my && (j+1) < t);
    rank += (lj[2] > my) || (lj[2] == my && (j+2) < t);
    rank += (lj[3] > my) || (lj[3] == my && (j+3) < t);
  }
  rnk[(size_t)b * T_ + t] = rank;
  if (rank < KTOK) idx[b * KTOK + rank] = t;
}

// ---------------- fused: pass-through unselected rows OR gather+LayerNorm selected --------
__global__ void __launch_bounds__(256) lnpass_kernel(const float* __restrict__ x,
    const int* __restrict__ rnk, const float* __restrict__ g, const float* __restrict__ bb,
    float* __restrict__ xs_out, u16* __restrict__ hout, float* __restrict__ out)
{
  int row = blockIdx.x;            // 0 .. B*T-1
  int tid = threadIdx.x;
  const float* srow = x + (size_t)row * D_;
  f32x4 v = *(const f32x4*)(srow + tid * 4);
  int r = rnk[row];
  if (r >= KTOK) {                 // unselected: copy x row to out (block-uniform branch)
    *(f32x4*)(out + (size_t)row * D_ + tid * 4) = v;
    return;
  }
  size_t mrow = (size_t)(row >> 12) * KTOK + r;   // T_=4096
  float s  = v[0] + v[1] + v[2] + v[3];
  float sq = v[0]*v[0] + v[1]*v[1] + v[2]*v[2] + v[3]*v[3];
#pragma unroll
  for (int d = 1; d < 64; d <<= 1) { s += __shfl_xor(s, d); sq += __shfl_xor(sq, d); }
  __shared__ float rs[4], rq[4];
  int lane = tid & 63, wave = tid >> 6;
  if (lane == 0) { rs[wave] = s; rq[wave] = sq; }
  __syncthreads();
  s  = rs[0] + rs[1] + rs[2] + rs[3];
  sq = rq[0] + rq[1] + rq[2] + rq[3];
  float mean = s * (1.0f / D_);
  float var  = sq * (1.0f / D_) - mean * mean;
  float rstd = rsqrtf(var + 1e-5f);
  f32x4 gg = *(const f32x4*)(g + tid * 4);
  f32x4 bv = *(const f32x4*)(bb + tid * 4);
  *(f32x4*)(xs_out + mrow * D_ + tid * 4) = v;
  u16x4 o;
#pragma unroll
  for (int j = 0; j < 4; j++) o[j] = f2bf((v[j] - mean) * rstd * gg[j] + bv[j]);
  *(u16x4*)(hout + mrow * D_ + tid * 4) = o;
}

// ---------------- LayerNorm (no gather) ----------------
__global__ void __launch_bounds__(256) ln2_kernel(const float* __restrict__ src,
    const float* __restrict__ g, const float* __restrict__ bb, u16* __restrict__ hout)
{
  int row = blockIdx.x;
  int tid = threadIdx.x;
  const float* srow = src + (size_t)row * D_;
  f32x4 v = *(const f32x4*)(srow + tid * 4);
  float s  = v[0] + v[1] + v[2] + v[3];
  float sq = v[0]*v[0] + v[1]*v[1] + v[2]*v[2] + v[3]*v[3];
#pragma unroll
  for (int d = 1; d < 64; d <<= 1) { s += __shfl_xor(s, d); sq += __shfl_xor(sq, d); }
  __shared__ float rs[4], rq[4];
  int lane = tid & 63, wave = tid >> 6;
  if (lane == 0) { rs[wave] = s; rq[wave] = sq; }
  __syncthreads();
  s  = rs[0] + rs[1] + rs[2] + rs[3];
  sq = rq[0] + rq[1] + rq[2] + rq[3];
  float mean = s * (1.0f / D_);
  float var  = sq * (1.0f / D_) - mean * mean;
  float rstd = rsqrtf(var + 1e-5f);
  f32x4 gg = *(const f32x4*)(g + tid * 4);
  f32x4 bv = *(const f32x4*)(bb + tid * 4);
  u16x4 o;
#pragma unroll
  for (int j = 0; j < 4; j++) o[j] = f2bf((v[j] - mean) * rstd * gg[j] + bv[j]);
  *(u16x4*)(hout + (size_t)row * D_ + tid * 4) = o;
}

// ---------------- fp32 -> bf16 convert, all 4 weight matrices in one dispatch ----------------
__global__ void __launch_bounds__(256) f2bf_all(const float* __restrict__ s0, const float* __restrict__ s1,
    const float* __restrict__ s2, const float* __restrict__ s3,
    u16* __restrict__ d0, u16* __restrict__ d1, u16* __restrict__ d2, u16* __restrict__ d3)
{
  const size_t c0 = (size_t)3 * D_ * D_, c1 = (size_t)4 * D_ * D_, c2 = (size_t)8 * D_ * D_;
  size_t e = (size_t)blockIdx.x * 1024 + (size_t)threadIdx.x * 4;
  const float* s; u16* d; size_t off;
  if (e < c0)      { s = s0; d = d0; off = e; }
  else if (e < c1) { s = s1; d = d1; off = e - c0; }
  else if (e < c2) { s = s2; d = d2; off = e - c1; }
  else             { s = s3; d = d3; off = e - c2; }
  f32x4 v = *(const f32x4*)(s + off);
  u16x4 o; o[0]=f2bf(v[0]); o[1]=f2bf(v[1]); o[2]=f2bf(v[2]); o[3]=f2bf(v[3]);
  *(u16x4*)(d + off) = o;
}

// ======================= 8-phase-style GEMM, BN=256, BK=64, 512 threads ====================
// C[M,N] = A[M,K](bf16) @ W[N,K]^T(bf16) + bias.  HA=2: BM=256 (4 phases/K-tile);
// HA=1: BM=128 (2 phases/K-tile).  Phases = C-quadrants (A-half x B-half); per phase each
// wave does 16 MFMA and stages ONE 16KB half-tile (2 global_load_lds dwordx4); counted
// vmcnt (never 0 in steady state) lets 3 half-tiles stay in flight across barriers.
// LDS both-sides swizzle: source col-chunk cc = (chunk ^ row) & 7, linear LDS dest,
// reads XOR the same -> 2-way bank conflicts (free).
// Wait ledger (2 loads/stage), stage order per tile t: [A0, B0, (B1, A1 | HA=2)]:
//   HA=2: enter p0: wait 4 (A0,B0 done); p1: wait 4 (B1); p2: wait 4 (A1); p3: none.
//         last tile: 4 / 2 / 0.
//   HA=1: enter p0: wait 2 (A,B0); p1: wait 2 (B1).  last tile: 2 / 0.
// Accumulation order per element is identical to the 128x128 BK=32 kernel (same 32-wide
// MFMA sequence in ascending K) -> bitwise-identical results.
template<int EPI, int HA>
__global__ void __launch_bounds__(512, 2) gemm256(
    const u16* __restrict__ A, const u16* __restrict__ W,
    const float* __restrict__ bias, float* __restrict__ xs,
    u16* __restrict__ Cb, float* __restrict__ outf,
    const int* __restrict__ idx, u16* __restrict__ vtb, int M, int N, int K)
{
  __shared__ u16 Asm[2][HA][128 * 64];
  __shared__ u16 Bsm[2][2][128 * 64];

  const int tid = threadIdx.x;
  const int lane = tid & 63;
  const int w = tid >> 6;                  // wave 0..7
  const int m16 = lane & 15, quad = (lane >> 4) & 3;
  const int rowA = (w >> 2) * 64;          // within A-half
  const int rowB = (w & 3) * 32;           // within B-half

  // chunked bijective XCD swizzle (grid size always divisible by 8)
  const int gx = gridDim.x;
  const int id = blockIdx.y * gx + blockIdx.x;
  const int cpx = (gx * (int)gridDim.y) >> 3;
  const int tl = (id & 7) * cpx + (id >> 3);
  const int bx = tl % gx, by = tl / gx;

  const int arow0 = by * (HA * 128);
  const int wcol0 = bx * 256;

  // staging: thread t handles chunks t and 512+t of a 1024-chunk (16KB) half-tile
  const int th8 = tid >> 3;                        // row within first 64
  const int ccs = (tid ^ th8) & 7;                 // swizzled source col-chunk
  auto stage = [&](const u16* g0, u16* l0) {       // g0 = mat + row0*K + k0
    gld_lds16(g0 + (size_t)th8 * K + ccs * 8,        l0 + (size_t)(tid & ~63) * 8);
    gld_lds16(g0 + (size_t)(64 + th8) * K + ccs * 8, l0 + 4096 + (size_t)(tid & ~63) * 8);
  };

  auto ldA = [&](short8 (&f)[4][2], const u16* h) {
#pragma unroll
    for (int mt = 0; mt < 4; mt++) {
      int rr = rowA + mt * 16 + m16;
      int sw = rr & 7;
#pragma unroll
      for (int kk = 0; kk < 2; kk++)
        f[mt][kk] = *(const short8*)&h[rr * 64 + (((kk * 4 + quad) ^ sw) * 8)];
    }
  };
  auto ldB = [&](short8 (&f)[2][2], const u16* h) {
#pragma unroll
    for (int nt = 0; nt < 2; nt++) {
      int rb = rowB + nt * 16 + m16;
      int sw = rb & 7;
#pragma unroll
      for (int kk = 0; kk < 2; kk++)
        f[nt][kk] = *(const short8*)&h[rb * 64 + (((kk * 4 + quad) ^ sw) * 8)];
    }
  };

  f32x4 acc[2 * HA][4][2];
#pragma unroll
  for (int q = 0; q < 2 * HA; q++)
#pragma unroll
    for (int mt = 0; mt < 4; mt++)
#pragma unroll
      for (int nt = 0; nt < 2; nt++) acc[q][mt][nt] = (f32x4)0.0f;

#define MMQ(QD, FA, FB) do { \
  __builtin_amdgcn_s_setprio(1); \
  _Pragma("unroll") for (int mt = 0; mt < 4; mt++) \
  _Pragma("unroll") for (int nt = 0; nt < 2; nt++) \
  _Pragma("unroll") for (int kk = 0; kk < 2; kk++) \
    acc[QD][mt][nt] = __builtin_amdgcn_mfma_f32_16x16x32_bf16(FA[mt][kk], FB[nt][kk], acc[QD][mt][nt], 0, 0, 0); \
  __builtin_amdgcn_s_setprio(0); } while (0)

  // prologue: tile 0, FIFO order [A0, B0, B1, (A1)]
  stage(A + (size_t)arow0 * K, &Asm[0][0][0]);
  stage(W + (size_t)wcol0 * K, &Bsm[0][0][0]);
  stage(W + (size_t)(wcol0 + 128) * K, &Bsm[0][1][0]);
  if constexpr (HA == 2) stage(A + (size_t)(arow0 + 128) * K, &Asm[0][1][0]);

  const int NT = K >> 6;
  short8 af[4][2], af2[4][2], bf[2][2], bf2[2][2];

  for (int t = 0; t < NT; t++) {
    const int cur = t & 1, nxt = cur ^ 1;
    const bool last = (t == NT - 1);
    const int kn = (t + 1) * 64;

    // ---- phase 0: quadrant (A0,B0) ----
    if constexpr (HA == 2) { WAITV(4); } else { WAITV(2); }
    __builtin_amdgcn_s_barrier();
    ldA(af, &Asm[cur][0][0]);
    ldB(bf, &Bsm[cur][0][0]);
    if (!last) stage(A + (size_t)arow0 * K + kn, &Asm[nxt][0][0]);
    MMQ(0, af, bf);

    // ---- phase 1: quadrant (A0,B1) ----
    if (!last) { if constexpr (HA == 2) { WAITV(4); } else { WAITV(2); } }
    else       { if constexpr (HA == 2) { WAITV(2); } else { WAITV(0); } }
    __builtin_amdgcn_s_barrier();
    ldB(bf2, &Bsm[cur][1][0]);
    if (!last) {
      stage(W + (size_t)wcol0 * K + kn, &Bsm[nxt][0][0]);
      if constexpr (HA == 1) stage(W + (size_t)(wcol0 + 128) * K + kn, &Bsm[nxt][1][0]);
    }
    MMQ(1, af, bf2);

    if constexpr (HA == 2) {
      // ---- phase 2: quadrant (A1,B0) ----
      if (!last) { WAITV(4); } else { WAITV(0); }
      __builtin_amdgcn_s_barrier();
      ldA(af2, &Asm[cur][1][0]);
      if (!last) stage(W + (size_t)(wcol0 + 128) * K + kn, &Bsm[nxt][1][0]);
      MMQ(2, af2, bf);
      // ---- phase 3: quadrant (A1,B1) ----
      if (!last) stage(A + (size_t)(arow0 + 128) * K + kn, &Asm[nxt][1][0]);
      MMQ(3, af2, bf2);
    }
  }
#undef MMQ

  // ---- epilogue ----
#pragma unroll
  for (int qd = 0; qd < 2 * HA; qd++) {
    const int ha = (HA == 2) ? (qd >> 1) : 0;
    const int hb = (HA == 2) ? (qd & 1) : qd;
#pragma unroll
    for (int mt = 0; mt < 4; mt++) {
#pragma unroll
      for (int nt = 0; nt < 2; nt++) {
        f32x4 a = acc[qd][mt][nt];
        size_t col = (size_t)wcol0 + hb * 128 + (w & 3) * 32 + nt * 16 + m16;
        float bvv = bias[col];
        size_t rowb = (size_t)arow0 + ha * 128 + (w >> 2) * 64 + mt * 16 + quad * 4;
        if (EPI == 0) {
          if ((int)col < 2 * D_) {
            float sc = ((int)col < D_) ? 0.18033688f : 1.0f;  // fold 1/sqrt(dh)*log2(e) into Q
#pragma unroll
            for (int r = 0; r < 4; r++)
              Cb[(rowb + r) * (size_t)N + col] = f2bf((a[r] + bvv) * sc);
          } else {
            int hdh = (int)col - 2 * D_;
            int bb2 = (int)(rowb >> 11);
            int tok = (int)(rowb & (KTOK - 1));
            u16x4 o;
#pragma unroll
            for (int r = 0; r < 4; r++) o[r] = f2bf(a[r] + bvv);
            *(u16x4*)&vtb[(((size_t)(bb2 * H_) + (hdh >> 6)) * 64 + (hdh & 63)) * KTOK + tok] = o;
          }
        } else if (EPI == 1) {
#pragma unroll
          for (int r = 0; r < 4; r++) {
            size_t o = (rowb + r) * (size_t)N + col;
            xs[o] = xs[o] + (a[r] + bvv);
          }
        } else if (EPI == 2) {
#pragma unroll
          for (int r = 0; r < 4; r++) {
            float v = a[r] + bvv;
            float gv = 0.5f * v * (1.0f + erff(v * 0.70710678118654752f));
            Cb[(rowb + r) * (size_t)N + col] = f2bf(gv);
          }
        } else {
#pragma unroll
          for (int r = 0; r < 4; r++) {
            size_t row = rowb + r;
            int b = (int)(row >> 11);
            int i = (int)(row & (KTOK - 1));
            int t = idx[b * KTOK + i];
            float vv = xs[row * (size_t)D_ + col] + (a[r] + bvv);
            outf[((size_t)b * T_ + t) * D_ + col] = vv;
          }
        }
      }
    }
  }
}

// ---------------- flash attention (unchanged from round 1) ----------------
#define PSTR 72
__global__ void __launch_bounds__(256, 3) attn_kernel(const u16* __restrict__ qkv,
                                                      const u16* __restrict__ vtb,
                                                      u16* __restrict__ obuf)
{
  __shared__ u16 Ks[2][64 * 64];     // 2 x 8192 B
  __shared__ u16 Vs[2][64 * 64];     // 2 x 8192 B
  __shared__ u16 Ps[4][16 * PSTR];   // 9216 B          total 42 KB -> 3 blocks/CU

  const int tid = threadIdx.x;
  const int lane = tid & 63, wave = tid >> 6;
  const int m16 = lane & 15, quad = lane >> 4;
  const int bh = blockIdx.x;
  const int b = bh >> 4, h = bh & 15;
  const int q0 = blockIdx.y * 128 + wave * 32;     // this wave: q0..q0+31

  const u16* base = qkv + ((size_t)b * KTOK) * (3 * D_) + h * DH_;
  const u16* vb   = vtb + (size_t)bh * 64 * KTOK;  // rows = dh, stride KTOK

  short8 qf[2][2];
#pragma unroll
  for (int qh = 0; qh < 2; qh++) {
    const u16* qrow = base + (size_t)(q0 + qh * 16 + m16) * (3 * D_);
    qf[qh][0] = *(const short8*)(qrow + quad * 8);
    qf[qh][1] = *(const short8*)(qrow + 32 + quad * 8);
  }

  f32x4 oacc[2][4];
#pragma unroll
  for (int qh = 0; qh < 2; qh++)
#pragma unroll
    for (int nt = 0; nt < 4; nt++) oacc[qh][nt] = (f32x4)0.0f;
  f32x4 lsum[2] = {(f32x4)0.0f, (f32x4)0.0f};

  auto stage_tile = [&](const u16* g0, size_t rstride, u16* lds) {
#pragma unroll
    for (int c = 0; c < 2; c++) {
      int g = c * 256 + tid;
      int key = g >> 3;
      int cc = (g ^ key) & 7;
      gld_lds16(g0 + (size_t)key * rstride + cc * 8,
                lds + (size_t)(c * 256 + (tid & ~63)) * 8);
    }
  };

  stage_tile(base + D_, 3 * D_, &Ks[0][0]);
  stage_tile(vb, KTOK, &Vs[0][0]);
  __syncthreads();

  int buf = 0;
  for (int tk = 0; tk < KTOK; tk += 64) {
    if (tk + 64 < KTOK) {
      stage_tile(base + (size_t)(tk + 64) * (3 * D_) + D_, 3 * D_, &Ks[buf ^ 1][0]);
      stage_tile(vb + (tk + 64), KTOK, &Vs[buf ^ 1][0]);
    }
    const u16* Kb = &Ks[buf][0];
    const u16* Vb = &Vs[buf][0];

    f32x4 sacc[2][4];
#pragma unroll
    for (int qh = 0; qh < 2; qh++)
#pragma unroll
      for (int nt = 0; nt < 4; nt++) sacc[qh][nt] = (f32x4)0.0f;
    __builtin_amdgcn_s_setprio(1);
#pragma unroll
    for (int nt = 0; nt < 4; nt++) {
      int row = nt * 16 + m16;
      int sw = row & 7;
      short8 kf0 = *(const short8*)&Kb[row * 64 + ((quad ^ sw) * 8)];
      short8 kf1 = *(const short8*)&Kb[row * 64 + (((4 + quad) ^ sw) * 8)];
#pragma unroll
      for (int qh = 0; qh < 2; qh++) {
        sacc[qh][nt] = __builtin_amdgcn_mfma_f32_16x16x32_bf16(kf0, qf[qh][0], sacc[qh][nt], 0, 0, 0);
        sacc[qh][nt] = __builtin_amdgcn_mfma_f32_16x16x32_bf16(kf1, qf[qh][1], sacc[qh][nt], 0, 0, 0);
      }
    }
    __builtin_amdgcn_s_setprio(0);

    short8 vf[4][2];
#pragma unroll
    for (int nt = 0; nt < 4; nt++) {
      int row = nt * 16 + m16;
      int sw = row & 7;
      vf[nt][0] = *(const short8*)&Vb[row * 64 + ((quad ^ sw) * 8)];
      vf[nt][1] = *(const short8*)&Vb[row * 64 + (((4 + quad) ^ sw) * 8)];
    }

#pragma unroll
    for (int qh = 0; qh < 2; qh++) {
#pragma unroll
      for (int nt = 0; nt < 4; nt++) {
        f32x4 p;
#pragma unroll
        for (int r = 0; r < 4; r++) p[r] = EXP2F(sacc[qh][nt][r]);
        lsum[qh] += p;
        u32x2 w2; w2[0] = pkbf_t(p[0], p[1]); w2[1] = pkbf_t(p[2], p[3]);
        *(u32x2*)&Ps[wave][m16 * PSTR + nt * 16 + quad * 4] = w2;
      }
      short8 pa0 = *(const short8*)&Ps[wave][m16 * PSTR + quad * 8];
      short8 pa1 = *(const short8*)&Ps[wave][m16 * PSTR + 32 + quad * 8];
      __builtin_amdgcn_s_setprio(1);
#pragma unroll
      for (int nt = 0; nt < 4; nt++) {
        oacc[qh][nt] = __builtin_amdgcn_mfma_f32_16x16x32_bf16(pa0, vf[nt][0], oacc[qh][nt], 0, 0, 0);
        oacc[qh][nt] = __builtin_amdgcn_mfma_f32_16x16x32_bf16(pa1, vf[nt][1], oacc[qh][nt], 0, 0, 0);
      }
      __builtin_amdgcn_s_setprio(0);
    }

    __syncthreads();
    buf ^= 1;
  }

  float rl[2][4];
#pragma unroll
  for (int qh = 0; qh < 2; qh++) {
    float l = (lsum[qh][0] + lsum[qh][1]) + (lsum[qh][2] + lsum[qh][3]);
    l += __shfl_xor(l, 16);
    l += __shfl_xor(l, 32);
#pragma unroll
    for (int r = 0; r < 4; r++) {
      float lr = __shfl(l, (lane & 48) | (quad * 4 + r));
      rl[qh][r] = 1.0f / lr;
    }
  }

#pragma unroll
  for (int qh = 0; qh < 2; qh++)
#pragma unroll
    for (int nt = 0; nt < 4; nt++)
#pragma unroll
      for (int r = 0; r < 4; r++) {
        int qq = q0 + qh * 16 + quad * 4 + r;
        float v = oacc[qh][nt][r] * rl[qh][r];
        obuf[((size_t)b * KTOK + qq) * D_ + h * DH_ + nt * 16 + m16] = f2bf(v);
      }
}

// ---------------- launch ----------------
extern "C" void kernel_launch(void* const* d_in, const int* in_sizes, int n_in,
                              void* d_out, int out_size, void* d_ws, size_t ws_size,
                              hipStream_t stream)
{
  (void)in_sizes; (void)n_in; (void)out_size; (void)ws_size;
  const float* x          = (const float*)d_in[0];
  const float* w_router   = (const float*)d_in[1];
  const float* in_proj_w  = (const float*)d_in[2];
  const float* in_proj_b  = (const float*)d_in[3];
  const float* out_proj_w = (const float*)d_in[4];
  const float* out_proj_b = (const float*)d_in[5];
  const float* w1         = (const float*)d_in[6];
  const float* b1         = (const float*)d_in[7];
  const float* w2         = (const float*)d_in[8];
  const float* b2         = (const float*)d_in[9];
  const float* ln1g       = (const float*)d_in[10];
  const float* ln1b       = (const float*)d_in[11];
  const float* ln2g       = (const float*)d_in[12];
  const float* ln2b       = (const float*)d_in[13];
  float* out = (float*)d_out;

  char* w = (char*)d_ws;
  auto alloc = [&](size_t bytes) -> char* {
    char* p = w; w += (bytes + 255) & ~(size_t)255; return p;
  };
  float* logits = (float*)alloc((size_t)B_ * T_ * 4);
  int*   rnk    = (int*)  alloc((size_t)B_ * T_ * 4);
  int*   idx    = (int*)  alloc((size_t)B_ * KTOK * 4);
  float* auxacc = (float*)alloc(256);
  u16* inpw  = (u16*)alloc((size_t)3 * D_ * D_ * 2);
  u16* outpw = (u16*)alloc((size_t)D_ * D_ * 2);
  u16* w1b   = (u16*)alloc((size_t)4 * D_ * D_ * 2);
  u16* w2b   = (u16*)alloc((size_t)4 * D_ * D_ * 2);
  float* xs  = (float*)alloc((size_t)MROWS * D_ * 4);
  u16* hbuf  = (u16*)alloc((size_t)MROWS * D_ * 2);
  char* region = alloc((size_t)MROWS * 4 * D_ * 2);      // 64 MB: qkv(48)+obuf(16), reused by ff
  u16* qkvb = (u16*)region;
  u16* obuf = (u16*)(region + (size_t)MROWS * 3 * D_ * 2);
  u16* ffb  = (u16*)region;
  u16* vtb  = (u16*)alloc((size_t)B_ * H_ * DH_ * KTOK * 2);   // 16 MB: V transposed [bh][dh][tok]

  (void)hipMemsetAsync(auxacc, 0, 4, stream);

  router_kernel<<<B_ * T_ / 4, 256, 0, stream>>>(x, w_router, logits, auxacc);
  rank_kernel<<<dim3(T_ / 256, B_), 256, 0, stream>>>(logits, rnk, idx, auxacc,
                                                      out + (size_t)B_ * T_ * D_);
  lnpass_kernel<<<B_ * T_, 256, 0, stream>>>(x, rnk, ln1g, ln1b, xs, hbuf, out);

  f2bf_all<<<12 * D_ * D_ / 1024, 256, 0, stream>>>(in_proj_w, out_proj_w, w1, w2,
                                                    inpw, outpw, w1b, w2b);

  gemm256<0, 1><<<dim3(3 * D_ / 256, MROWS / 128), 512, 0, stream>>>(
      hbuf, inpw, in_proj_b, nullptr, qkvb, nullptr, nullptr, vtb, MROWS, 3 * D_, D_);
  attn_kernel<<<dim3(B_ * H_, KTOK / 128), 256, 0, stream>>>(qkvb, vtb, obuf);
  gemm256<1, 1><<<dim3(D_ / 256, MROWS / 128), 512, 0, stream>>>(
      obuf, outpw, out_proj_b, xs, nullptr, nullptr, nullptr, nullptr, MROWS, D_, D_);
  ln2_kernel<<<MROWS, 256, 0, stream>>>(xs, ln2g, ln2b, hbuf);
  gemm256<2, 2><<<dim3(4 * D_ / 256, MROWS / 256), 512, 0, stream>>>(
      hbuf, w1b, b1, nullptr, ffb, nullptr, nullptr, nullptr, MROWS, 4 * D_, D_);
  gemm256<3, 1><<<dim3(D_ / 256, MROWS / 128), 512, 0, stream>>>(
      ffb, w2b, b2, xs, nullptr, out, idx, nullptr, MROWS, D_, 4 * D_);
}

// Round 4
// 738.965 us; speedup vs baseline: 1.0851x; 1.0851x over previous
//
#include <hip/hip_runtime.h>

#define B_    4
#define T_    4096
#define D_    1024
#define H_    16
#define DH_   64
#define KTOK  2048
#define MROWS (B_*KTOK)   // 8192

typedef unsigned short u16;
typedef __attribute__((ext_vector_type(8))) short short8;
typedef __attribute__((ext_vector_type(4))) float f32x4;
typedef __attribute__((ext_vector_type(4))) unsigned int u32x4;
typedef __attribute__((ext_vector_type(2))) unsigned int u32x2;
typedef __attribute__((ext_vector_type(4))) unsigned short u16x4;

static __device__ __forceinline__ u16 f2bf(float f) {
  union { float f; unsigned int u; } a; a.f = f;
  unsigned int u = a.u;
  unsigned int r = (u + 0x7FFFu + ((u >> 16) & 1u)) >> 16;   // RNE
  return (u16)r;
}

#if defined(__has_builtin)
#if __has_builtin(__builtin_amdgcn_exp2f)
#define EXP2F(x) __builtin_amdgcn_exp2f(x)
#endif
#endif
#ifndef EXP2F
#define EXP2F(x) exp2f(x)
#endif

// fast erf-based gelu: Abramowitz-Stegun 7.1.26, |err(erf)| < 2e-7 (vs bf16 ulp ~4e-3)
static __device__ __forceinline__ float gelu_f(float v) {
  float x = fabsf(v) * 0.70710678118654752f;
  float t = __builtin_amdgcn_rcpf(1.0f + 0.3275911f * x);
  float p = t * (0.254829592f + t * (-0.284496736f + t * (1.421413741f +
            t * (-1.453152027f + t * 1.061405429f))));
  float e = EXP2F(-1.4426950408889634f * x * x);
  float er = 1.0f - p * e;                    // erf(|x|)
  er = (v < 0.0f) ? -er : er;
  return 0.5f * v * (1.0f + er);
}

// pack two fp32 -> adjacent bf16 pair (low = a), TRUNCATING (1 v_perm).
static __device__ __forceinline__ unsigned int pkbf_t(float a, float b) {
  unsigned int ua = __builtin_bit_cast(unsigned int, a);
  unsigned int ub = __builtin_bit_cast(unsigned int, b);
  return __builtin_amdgcn_perm(ub, ua, 0x07060302u);  // [ua.hi16 low, ub.hi16 high]
}

static __device__ __forceinline__ void gld_lds16(const u16* g, u16* l) {
  __builtin_amdgcn_global_load_lds((__attribute__((address_space(1))) void*)g,
                                   (__attribute__((address_space(3))) void*)l, 16, 0, 0);
}

#define WAITV(N) asm volatile("s_waitcnt vmcnt(" #N ")" ::: "memory")

// ---------------- router: logits = x @ w_router, accumulate sum(logits^2) ----------------
__global__ void __launch_bounds__(256) router_kernel(const float* __restrict__ x,
    const float* __restrict__ wr, float* __restrict__ logits, float* __restrict__ auxacc)
{
  int tid = threadIdx.x; int lane = tid & 63, wave = tid >> 6;
  int row = blockIdx.x * 4 + wave;                 // 0 .. B*T-1
  const float* xr = x + (size_t)row * D_;
  float dot = 0.f;
#pragma unroll
  for (int j = 0; j < 4; j++) {
    int c = j * 256 + lane * 4;
    f32x4 xv = *(const f32x4*)(xr + c);
    f32x4 wv = *(const f32x4*)(wr + c);
    dot += xv[0]*wv[0] + xv[1]*wv[1] + xv[2]*wv[2] + xv[3]*wv[3];
  }
#pragma unroll
  for (int d = 1; d < 64; d <<= 1) dot += __shfl_xor(dot, d);
  __shared__ float red[4];
  if (lane == 0) { logits[row] = dot; red[wave] = dot; }
  __syncthreads();
  if (tid == 0) {
    float a = red[0]*red[0] + red[1]*red[1] + red[2]*red[2] + red[3]*red[3];
    atomicAdd(auxacc, a);
  }
}

// ---------------- rank: write RANK per token (rank<KTOK => selected, slot=rank) -----------
__global__ void __launch_bounds__(256) rank_kernel(const float* __restrict__ logits,
    int* __restrict__ rnk, int* __restrict__ idx,
    const float* __restrict__ acc, float* __restrict__ auxout)
{
  __shared__ float ll[T_];
  int b = blockIdx.y;
  int tid = threadIdx.x;
  if (b == 0 && blockIdx.x == 0 && tid == 0)
    auxout[0] = acc[0] * (0.01f / (float)(B_ * T_));
  const float* lg = logits + (size_t)b * T_;
  for (int j = tid; j < T_; j += 256) ll[j] = lg[j];
  __syncthreads();
  int t = blockIdx.x * 256 + tid;
  float my = ll[t];
  int rank = 0;
  for (int j = 0; j < T_; j += 4) {
    f32x4 lj = *(const f32x4*)&ll[j];
    rank += (lj[0] > my) || (lj[0] == my && (j+0) < t);
    rank += (lj[1] > my) || (lj[1] == my && (j+1) < t);
    rank += (lj[2] > my) || (lj[2] == my && (j+2) < t);
    rank += (lj[3] > my) || (lj[3] == my && (j+3) < t);
  }
  rnk[(size_t)b * T_ + t] = rank;
  if (rank < KTOK) idx[b * KTOK + rank] = t;
}

// ---------------- fused: pass-through unselected rows OR gather+LayerNorm selected --------
__global__ void __launch_bounds__(256) lnpass_kernel(const float* __restrict__ x,
    const int* __restrict__ rnk, const float* __restrict__ g, const float* __restrict__ bb,
    float* __restrict__ xs_out, u16* __restrict__ hout, float* __restrict__ out)
{
  int row = blockIdx.x;            // 0 .. B*T-1
  int tid = threadIdx.x;
  const float* srow = x + (size_t)row * D_;
  f32x4 v = *(const f32x4*)(srow + tid * 4);
  int r = rnk[row];
  if (r >= KTOK) {                 // unselected: copy x row to out (block-uniform branch)
    *(f32x4*)(out + (size_t)row * D_ + tid * 4) = v;
    return;
  }
  size_t mrow = (size_t)(row >> 12) * KTOK + r;   // T_=4096
  float s  = v[0] + v[1] + v[2] + v[3];
  float sq = v[0]*v[0] + v[1]*v[1] + v[2]*v[2] + v[3]*v[3];
#pragma unroll
  for (int d = 1; d < 64; d <<= 1) { s += __shfl_xor(s, d); sq += __shfl_xor(sq, d); }
  __shared__ float rs[4], rq[4];
  int lane = tid & 63, wave = tid >> 6;
  if (lane == 0) { rs[wave] = s; rq[wave] = sq; }
  __syncthreads();
  s  = rs[0] + rs[1] + rs[2] + rs[3];
  sq = rq[0] + rq[1] + rq[2] + rq[3];
  float mean = s * (1.0f / D_);
  float var  = sq * (1.0f / D_) - mean * mean;
  float rstd = rsqrtf(var + 1e-5f);
  f32x4 gg = *(const f32x4*)(g + tid * 4);
  f32x4 bv = *(const f32x4*)(bb + tid * 4);
  *(f32x4*)(xs_out + mrow * D_ + tid * 4) = v;
  u16x4 o;
#pragma unroll
  for (int j = 0; j < 4; j++) o[j] = f2bf((v[j] - mean) * rstd * gg[j] + bv[j]);
  *(u16x4*)(hout + mrow * D_ + tid * 4) = o;
}

// ---------------- LayerNorm (no gather) ----------------
__global__ void __launch_bounds__(256) ln2_kernel(const float* __restrict__ src,
    const float* __restrict__ g, const float* __restrict__ bb, u16* __restrict__ hout)
{
  int row = blockIdx.x;
  int tid = threadIdx.x;
  const float* srow = src + (size_t)row * D_;
  f32x4 v = *(const f32x4*)(srow + tid * 4);
  float s  = v[0] + v[1] + v[2] + v[3];
  float sq = v[0]*v[0] + v[1]*v[1] + v[2]*v[2] + v[3]*v[3];
#pragma unroll
  for (int d = 1; d < 64; d <<= 1) { s += __shfl_xor(s, d); sq += __shfl_xor(sq, d); }
  __shared__ float rs[4], rq[4];
  int lane = tid & 63, wave = tid >> 6;
  if (lane == 0) { rs[wave] = s; rq[wave] = sq; }
  __syncthreads();
  s  = rs[0] + rs[1] + rs[2] + rs[3];
  sq = rq[0] + rq[1] + rq[2] + rq[3];
  float mean = s * (1.0f / D_);
  float var  = sq * (1.0f / D_) - mean * mean;
  float rstd = rsqrtf(var + 1e-5f);
  f32x4 gg = *(const f32x4*)(g + tid * 4);
  f32x4 bv = *(const f32x4*)(bb + tid * 4);
  u16x4 o;
#pragma unroll
  for (int j = 0; j < 4; j++) o[j] = f2bf((v[j] - mean) * rstd * gg[j] + bv[j]);
  *(u16x4*)(hout + (size_t)row * D_ + tid * 4) = o;
}

// ---------------- fp32 -> bf16 convert, all 4 weight matrices in one dispatch ----------------
__global__ void __launch_bounds__(256) f2bf_all(const float* __restrict__ s0, const float* __restrict__ s1,
    const float* __restrict__ s2, const float* __restrict__ s3,
    u16* __restrict__ d0, u16* __restrict__ d1, u16* __restrict__ d2, u16* __restrict__ d3)
{
  const size_t c0 = (size_t)3 * D_ * D_, c1 = (size_t)4 * D_ * D_, c2 = (size_t)8 * D_ * D_;
  size_t e = (size_t)blockIdx.x * 1024 + (size_t)threadIdx.x * 4;
  const float* s; u16* d; size_t off;
  if (e < c0)      { s = s0; d = d0; off = e; }
  else if (e < c1) { s = s1; d = d1; off = e - c0; }
  else if (e < c2) { s = s2; d = d2; off = e - c1; }
  else             { s = s3; d = d3; off = e - c2; }
  f32x4 v = *(const f32x4*)(s + off);
  u16x4 o; o[0]=f2bf(v[0]); o[1]=f2bf(v[1]); o[2]=f2bf(v[2]); o[3]=f2bf(v[3]);
  *(u16x4*)(d + off) = o;
}

// ---------------- GEMM (proven round-2 structure): 128x128, BK=32, dbuf, 1 barrier/step ----
// EPI 0: bf16 to Cb; Q cols pre-scaled; V cols transposed to vtb[bh][dh][tok]
// EPI 1: v += xs (fp32 residual), write fp32 to xs (in place)
// EPI 3: v += xs residual, scatter-write fp32 rows into outf at token idx
template<int EPI>
__global__ void __launch_bounds__(256, 2) gemm_bt(
    const u16* __restrict__ A, const u16* __restrict__ W,
    const float* __restrict__ bias, float* __restrict__ xs,
    u16* __restrict__ Cb, float* __restrict__ outf,
    const int* __restrict__ idx, u16* __restrict__ vtb, int M, int N, int K)
{
  __shared__ u16 As[2][128 * 32];
  __shared__ u16 Ws[2][128 * 32];
  const int tid = threadIdx.x;
  const int lane = tid & 63, wave = tid >> 6;
  const int wm = wave >> 1, wn = wave & 1;
  const int m16 = lane & 15, quad = lane >> 4;

  // chunked XCD swizzle (grid divisible by 8)
  const int gx = gridDim.x;
  const int id = blockIdx.y * gx + blockIdx.x;
  const int cpx = (gx * (int)gridDim.y) >> 3;
  const int tl = (id & 7) * cpx + (id >> 3);
  const int bx = tl % gx, by = tl / gx;

  const size_t arow0 = (size_t)by * 128;
  const size_t wrow0 = (size_t)bx * 128;
  const int r4 = lane >> 2, c8 = (lane & 3) * 8;

  const u16* ag0 = A + (arow0 + wave * 16 + r4) * (size_t)K + c8;
  const u16* ag1 = ag0 + (size_t)64 * K;
  const u16* wg0 = W + (wrow0 + wave * 16 + r4) * (size_t)K + c8;
  const u16* wg1 = wg0 + (size_t)64 * K;

  auto stage = [&](int k0, int s) {
    gld_lds16(ag0 + k0, &As[s][0] + (wave * 16) * 32);
    gld_lds16(ag1 + k0, &As[s][0] + (64 + wave * 16) * 32);
    gld_lds16(wg0 + k0, &Ws[s][0] + (wave * 16) * 32);
    gld_lds16(wg1 + k0, &Ws[s][0] + (64 + wave * 16) * 32);
  };

  f32x4 acc[4][4];
#pragma unroll
  for (int i = 0; i < 4; i++)
#pragma unroll
    for (int j = 0; j < 4; j++) acc[i][j] = (f32x4)0.0f;

  stage(0, 0);
  __syncthreads();
  int cur = 0;
  for (int k0 = 0; k0 < K; k0 += 32) {
    if (k0 + 32 < K) stage(k0 + 32, cur ^ 1);   // prefetch hidden under this step's compute
    short8 af[4], wf[4];
#pragma unroll
    for (int mt = 0; mt < 4; mt++)
      af[mt] = *(const short8*)(&As[cur][0] + (wm * 64 + mt * 16 + m16) * 32 + quad * 8);
#pragma unroll
    for (int nt = 0; nt < 4; nt++)
      wf[nt] = *(const short8*)(&Ws[cur][0] + (wn * 64 + nt * 16 + m16) * 32 + quad * 8);
#pragma unroll
    for (int mt = 0; mt < 4; mt++)
#pragma unroll
      for (int nt = 0; nt < 4; nt++)
        acc[mt][nt] = __builtin_amdgcn_mfma_f32_16x16x32_bf16(af[mt], wf[nt], acc[mt][nt], 0, 0, 0);
    __syncthreads();
    cur ^= 1;
  }

#pragma unroll
  for (int mt = 0; mt < 4; mt++) {
#pragma unroll
    for (int nt = 0; nt < 4; nt++) {
      f32x4 a = acc[mt][nt];
      size_t col = wrow0 + wn * 64 + nt * 16 + m16;
      float bvv = bias[col];
      size_t rowb = arow0 + wm * 64 + mt * 16 + quad * 4;
      if (EPI == 0) {
        if ((int)col < 2 * D_) {
          float sc = ((int)col < D_) ? 0.18033688f : 1.0f;  // fold 1/sqrt(dh)*log2(e) into Q
#pragma unroll
          for (int r = 0; r < 4; r++)
            Cb[(rowb + r) * (size_t)N + col] = f2bf((a[r] + bvv) * sc);
        } else {
          int hdh = (int)col - 2 * D_;
          int bb2 = (int)(rowb >> 11);
          int tok = (int)(rowb & (KTOK - 1));
          u16x4 o;
#pragma unroll
          for (int r = 0; r < 4; r++) o[r] = f2bf(a[r] + bvv);
          *(u16x4*)&vtb[(((size_t)(bb2 * H_) + (hdh >> 6)) * 64 + (hdh & 63)) * KTOK + tok] = o;
        }
      } else if (EPI == 1) {
#pragma unroll
        for (int r = 0; r < 4; r++) {
          size_t o = (rowb + r) * (size_t)N + col;
          xs[o] = xs[o] + (a[r] + bvv);
        }
      } else {
#pragma unroll
        for (int r = 0; r < 4; r++) {
          size_t row = rowb + r;
          int b = (int)(row >> 11);
          int i = (int)(row & (KTOK - 1));
          int t = idx[b * KTOK + i];
          float vv = xs[row * (size_t)D_ + col] + (a[r] + bvv);
          outf[((size_t)b * T_ + t) * D_ + col] = vv;
        }
      }
    }
  }
}

// ================= FF1 GEMM: 256x256, BK=64, 512 threads, deep-prefetch schedule ===========
// Stage ALL 4 half-tiles of K-tile t+1 at the TOP of tile t (FIFO: A0,B0,A1,B1) so the data
// each wait needs was issued a FULL TILE (~650+ cy) earlier — covers L2 (~300cy) fully and
// most of the HBM tail (~900cy).  Only 2 counted waits + 2 barriers per 64 MFMA:
//   top: vmcnt(4) -> A0,B0(t) done (A1,B1(t) still allowed in flight)
//   mid: vmcnt(8) -> A1,B1(t) done (the 8 just-issued t+1 loads in flight)
// Phases p1..p3 are barrier-free: waves drift, ds_read/MFMA/stage overlap across waves.
// LDS both-sides swizzle (round-3, verified): src chunk cc=(c^row)&7, linear dest, read XORs.
// Accumulation order bitwise-identical to gemm_bt.  Epilogue: fast-erf gelu -> bf16.
__global__ void __launch_bounds__(512, 1) gemm_ff1(
    const u16* __restrict__ A, const u16* __restrict__ W,
    const float* __restrict__ bias, u16* __restrict__ Cb, int M, int N, int K)
{
  __shared__ u16 Asm[2][2][128 * 64];
  __shared__ u16 Bsm[2][2][128 * 64];

  const int tid = threadIdx.x;
  const int lane = tid & 63;
  const int w = tid >> 6;                  // wave 0..7
  const int m16 = lane & 15, quad = (lane >> 4) & 3;
  const int rowA = (w >> 2) * 64;          // within A-half
  const int rowB = (w & 3) * 32;           // within B-half

  const int gx = gridDim.x;
  const int id = blockIdx.y * gx + blockIdx.x;
  const int cpx = (gx * (int)gridDim.y) >> 3;
  const int tl = (id & 7) * cpx + (id >> 3);
  const int bx = tl % gx, by = tl / gx;

  const int arow0 = by * 256;
  const int wcol0 = bx * 256;

  const int th8 = tid >> 3;
  const int ccs = (tid ^ th8) & 7;
  auto stage = [&](const u16* g0, u16* l0) {       // one 128x64 half-tile (16KB), 2 loads/thread
    gld_lds16(g0 + (size_t)th8 * K + ccs * 8,        l0 + (size_t)(tid & ~63) * 8);
    gld_lds16(g0 + (size_t)(64 + th8) * K + ccs * 8, l0 + 4096 + (size_t)(tid & ~63) * 8);
  };
  auto stage_tile = [&](int u, int s) {            // FIFO order: A0, B0, A1, B1
    size_t kn = (size_t)u * 64;
    stage(A + (size_t)arow0 * K + kn,         &Asm[s][0][0]);
    stage(W + (size_t)wcol0 * K + kn,         &Bsm[s][0][0]);
    stage(A + (size_t)(arow0 + 128) * K + kn, &Asm[s][1][0]);
    stage(W + (size_t)(wcol0 + 128) * K + kn, &Bsm[s][1][0]);
  };

  auto ldA = [&](short8 (&f)[4][2], const u16* h) {
#pragma unroll
    for (int mt = 0; mt < 4; mt++) {
      int rr = rowA + mt * 16 + m16;
      int sw = rr & 7;
#pragma unroll
      for (int kk = 0; kk < 2; kk++)
        f[mt][kk] = *(const short8*)&h[rr * 64 + (((kk * 4 + quad) ^ sw) * 8)];
    }
  };
  auto ldB = [&](short8 (&f)[2][2], const u16* h) {
#pragma unroll
    for (int nt = 0; nt < 2; nt++) {
      int rb = rowB + nt * 16 + m16;
      int sw = rb & 7;
#pragma unroll
      for (int kk = 0; kk < 2; kk++)
        f[nt][kk] = *(const short8*)&h[rb * 64 + (((kk * 4 + quad) ^ sw) * 8)];
    }
  };

  f32x4 acc[4][4][2];
#pragma unroll
  for (int q = 0; q < 4; q++)
#pragma unroll
    for (int mt = 0; mt < 4; mt++)
#pragma unroll
      for (int nt = 0; nt < 2; nt++) acc[q][mt][nt] = (f32x4)0.0f;

#define MMQ(QD, FA, FB) do { \
  __builtin_amdgcn_s_setprio(1); \
  _Pragma("unroll") for (int mt = 0; mt < 4; mt++) \
  _Pragma("unroll") for (int nt = 0; nt < 2; nt++) \
  _Pragma("unroll") for (int kk = 0; kk < 2; kk++) \
    acc[QD][mt][nt] = __builtin_amdgcn_mfma_f32_16x16x32_bf16(FA[mt][kk], FB[nt][kk], acc[QD][mt][nt], 0, 0, 0); \
  __builtin_amdgcn_s_setprio(0); } while (0)

  stage_tile(0, 0);

  const int NT = K >> 6;
  short8 af[4][2], af2[4][2], bf[2][2], bf2[2][2];

  for (int t = 0; t < NT; t++) {
    const int cur = t & 1;
    const bool last = (t == NT - 1);

    WAITV(4);                                   // A0,B0(t) done; A1,B1(t) may be in flight
    __builtin_amdgcn_s_barrier();
    __builtin_amdgcn_sched_barrier(0);
    if (!last) stage_tile(t + 1, cur ^ 1);      // 8 loads; slots freed by this barrier

    // p0: (A0,B0)
    ldA(af, &Asm[cur][0][0]);
    ldB(bf, &Bsm[cur][0][0]);
    MMQ(0, af, bf);

    if (last) { WAITV(0); } else { WAITV(8); }  // A1,B1(t) done; t+1's 8 loads in flight
    __builtin_amdgcn_s_barrier();
    __builtin_amdgcn_sched_barrier(0);

    // p1..p3: barrier-free drift region
    ldB(bf2, &Bsm[cur][1][0]);
    MMQ(1, af, bf2);
    ldA(af2, &Asm[cur][1][0]);
    MMQ(2, af2, bf);
    MMQ(3, af2, bf2);
  }
#undef MMQ

  // ---- epilogue: gelu(bf16) ----
#pragma unroll
  for (int qd = 0; qd < 4; qd++) {
    const int ha = qd >> 1, hb = qd & 1;
#pragma unroll
    for (int mt = 0; mt < 4; mt++) {
#pragma unroll
      for (int nt = 0; nt < 2; nt++) {
        f32x4 a = acc[qd][mt][nt];
        size_t col = (size_t)wcol0 + hb * 128 + (w & 3) * 32 + nt * 16 + m16;
        float bvv = bias[col];
        size_t rowb = (size_t)arow0 + ha * 128 + (w >> 2) * 64 + mt * 16 + quad * 4;
#pragma unroll
        for (int r = 0; r < 4; r++)
          Cb[(rowb + r) * (size_t)N + col] = f2bf(gelu_f(a[r] + bvv));
      }
    }
  }
}

// ---------------- flash attention (unchanged) ----------------
#define PSTR 72
__global__ void __launch_bounds__(256, 3) attn_kernel(const u16* __restrict__ qkv,
                                                      const u16* __restrict__ vtb,
                                                      u16* __restrict__ obuf)
{
  __shared__ u16 Ks[2][64 * 64];     // 2 x 8192 B
  __shared__ u16 Vs[2][64 * 64];     // 2 x 8192 B
  __shared__ u16 Ps[4][16 * PSTR];   // 9216 B          total 42 KB -> 3 blocks/CU

  const int tid = threadIdx.x;
  const int lane = tid & 63, wave = tid >> 6;
  const int m16 = lane & 15, quad = lane >> 4;
  const int bh = blockIdx.x;
  const int b = bh >> 4, h = bh & 15;
  const int q0 = blockIdx.y * 128 + wave * 32;     // this wave: q0..q0+31

  const u16* base = qkv + ((size_t)b * KTOK) * (3 * D_) + h * DH_;
  const u16* vb   = vtb + (size_t)bh * 64 * KTOK;  // rows = dh, stride KTOK

  short8 qf[2][2];
#pragma unroll
  for (int qh = 0; qh < 2; qh++) {
    const u16* qrow = base + (size_t)(q0 + qh * 16 + m16) * (3 * D_);
    qf[qh][0] = *(const short8*)(qrow + quad * 8);
    qf[qh][1] = *(const short8*)(qrow + 32 + quad * 8);
  }

  f32x4 oacc[2][4];
#pragma unroll
  for (int qh = 0; qh < 2; qh++)
#pragma unroll
    for (int nt = 0; nt < 4; nt++) oacc[qh][nt] = (f32x4)0.0f;
  f32x4 lsum[2] = {(f32x4)0.0f, (f32x4)0.0f};

  auto stage_tile = [&](const u16* g0, size_t rstride, u16* lds) {
#pragma unroll
    for (int c = 0; c < 2; c++) {
      int g = c * 256 + tid;
      int key = g >> 3;
      int cc = (g ^ key) & 7;
      gld_lds16(g0 + (size_t)key * rstride + cc * 8,
                lds + (size_t)(c * 256 + (tid & ~63)) * 8);
    }
  };

  stage_tile(base + D_, 3 * D_, &Ks[0][0]);
  stage_tile(vb, KTOK, &Vs[0][0]);
  __syncthreads();

  int buf = 0;
  for (int tk = 0; tk < KTOK; tk += 64) {
    if (tk + 64 < KTOK) {
      stage_tile(base + (size_t)(tk + 64) * (3 * D_) + D_, 3 * D_, &Ks[buf ^ 1][0]);
      stage_tile(vb + (tk + 64), KTOK, &Vs[buf ^ 1][0]);
    }
    const u16* Kb = &Ks[buf][0];
    const u16* Vb = &Vs[buf][0];

    f32x4 sacc[2][4];
#pragma unroll
    for (int qh = 0; qh < 2; qh++)
#pragma unroll
      for (int nt = 0; nt < 4; nt++) sacc[qh][nt] = (f32x4)0.0f;
    __builtin_amdgcn_s_setprio(1);
#pragma unroll
    for (int nt = 0; nt < 4; nt++) {
      int row = nt * 16 + m16;
      int sw = row & 7;
      short8 kf0 = *(const short8*)&Kb[row * 64 + ((quad ^ sw) * 8)];
      short8 kf1 = *(const short8*)&Kb[row * 64 + (((4 + quad) ^ sw) * 8)];
#pragma unroll
      for (int qh = 0; qh < 2; qh++) {
        sacc[qh][nt] = __builtin_amdgcn_mfma_f32_16x16x32_bf16(kf0, qf[qh][0], sacc[qh][nt], 0, 0, 0);
        sacc[qh][nt] = __builtin_amdgcn_mfma_f32_16x16x32_bf16(kf1, qf[qh][1], sacc[qh][nt], 0, 0, 0);
      }
    }
    __builtin_amdgcn_s_setprio(0);

    short8 vf[4][2];
#pragma unroll
    for (int nt = 0; nt < 4; nt++) {
      int row = nt * 16 + m16;
      int sw = row & 7;
      vf[nt][0] = *(const short8*)&Vb[row * 64 + ((quad ^ sw) * 8)];
      vf[nt][1] = *(const short8*)&Vb[row * 64 + (((4 + quad) ^ sw) * 8)];
    }

#pragma unroll
    for (int qh = 0; qh < 2; qh++) {
#pragma unroll
      for (int nt = 0; nt < 4; nt++) {
        f32x4 p;
#pragma unroll
        for (int r = 0; r < 4; r++) p[r] = EXP2F(sacc[qh][nt][r]);
        lsum[qh] += p;
        u32x2 w2; w2[0] = pkbf_t(p[0], p[1]); w2[1] = pkbf_t(p[2], p[3]);
        *(u32x2*)&Ps[wave][m16 * PSTR + nt * 16 + quad * 4] = w2;
      }
      short8 pa0 = *(const short8*)&Ps[wave][m16 * PSTR + quad * 8];
      short8 pa1 = *(const short8*)&Ps[wave][m16 * PSTR + 32 + quad * 8];
      __builtin_amdgcn_s_setprio(1);
#pragma unroll
      for (int nt = 0; nt < 4; nt++) {
        oacc[qh][nt] = __builtin_amdgcn_mfma_f32_16x16x32_bf16(pa0, vf[nt][0], oacc[qh][nt], 0, 0, 0);
        oacc[qh][nt] = __builtin_amdgcn_mfma_f32_16x16x32_bf16(pa1, vf[nt][1], oacc[qh][nt], 0, 0, 0);
      }
      __builtin_amdgcn_s_setprio(0);
    }

    __syncthreads();
    buf ^= 1;
  }

  float rl[2][4];
#pragma unroll
  for (int qh = 0; qh < 2; qh++) {
    float l = (lsum[qh][0] + lsum[qh][1]) + (lsum[qh][2] + lsum[qh][3]);
    l += __shfl_xor(l, 16);
    l += __shfl_xor(l, 32);
#pragma unroll
    for (int r = 0; r < 4; r++) {
      float lr = __shfl(l, (lane & 48) | (quad * 4 + r));
      rl[qh][r] = 1.0f / lr;
    }
  }

#pragma unroll
  for (int qh = 0; qh < 2; qh++)
#pragma unroll
    for (int nt = 0; nt < 4; nt++)
#pragma unroll
      for (int r = 0; r < 4; r++) {
        int qq = q0 + qh * 16 + quad * 4 + r;
        float v = oacc[qh][nt][r] * rl[qh][r];
        obuf[((size_t)b * KTOK + qq) * D_ + h * DH_ + nt * 16 + m16] = f2bf(v);
      }
}

// ---------------- launch ----------------
extern "C" void kernel_launch(void* const* d_in, const int* in_sizes, int n_in,
                              void* d_out, int out_size, void* d_ws, size_t ws_size,
                              hipStream_t stream)
{
  (void)in_sizes; (void)n_in; (void)out_size; (void)ws_size;
  const float* x          = (const float*)d_in[0];
  const float* w_router   = (const float*)d_in[1];
  const float* in_proj_w  = (const float*)d_in[2];
  const float* in_proj_b  = (const float*)d_in[3];
  const float* out_proj_w = (const float*)d_in[4];
  const float* out_proj_b = (const float*)d_in[5];
  const float* w1         = (const float*)d_in[6];
  const float* b1         = (const float*)d_in[7];
  const float* w2         = (const float*)d_in[8];
  const float* b2         = (const float*)d_in[9];
  const float* ln1g       = (const float*)d_in[10];
  const float* ln1b       = (const float*)d_in[11];
  const float* ln2g       = (const float*)d_in[12];
  const float* ln2b       = (const float*)d_in[13];
  float* out = (float*)d_out;

  char* w = (char*)d_ws;
  auto alloc = [&](size_t bytes) -> char* {
    char* p = w; w += (bytes + 255) & ~(size_t)255; return p;
  };
  float* logits = (float*)alloc((size_t)B_ * T_ * 4);
  int*   rnk    = (int*)  alloc((size_t)B_ * T_ * 4);
  int*   idx    = (int*)  alloc((size_t)B_ * KTOK * 4);
  float* auxacc = (float*)alloc(256);
  u16* inpw  = (u16*)alloc((size_t)3 * D_ * D_ * 2);
  u16* outpw = (u16*)alloc((size_t)D_ * D_ * 2);
  u16* w1b   = (u16*)alloc((size_t)4 * D_ * D_ * 2);
  u16* w2b   = (u16*)alloc((size_t)4 * D_ * D_ * 2);
  float* xs  = (float*)alloc((size_t)MROWS * D_ * 4);
  u16* hbuf  = (u16*)alloc((size_t)MROWS * D_ * 2);
  char* region = alloc((size_t)MROWS * 4 * D_ * 2);      // 64 MB: qkv(48)+obuf(16), reused by ff
  u16* qkvb = (u16*)region;
  u16* obuf = (u16*)(region + (size_t)MROWS * 3 * D_ * 2);
  u16* ffb  = (u16*)region;
  u16* vtb  = (u16*)alloc((size_t)B_ * H_ * DH_ * KTOK * 2);   // 16 MB: V transposed [bh][dh][tok]

  (void)hipMemsetAsync(auxacc, 0, 4, stream);

  router_kernel<<<B_ * T_ / 4, 256, 0, stream>>>(x, w_router, logits, auxacc);
  rank_kernel<<<dim3(T_ / 256, B_), 256, 0, stream>>>(logits, rnk, idx, auxacc,
                                                      out + (size_t)B_ * T_ * D_);
  lnpass_kernel<<<B_ * T_, 256, 0, stream>>>(x, rnk, ln1g, ln1b, xs, hbuf, out);

  f2bf_all<<<12 * D_ * D_ / 1024, 256, 0, stream>>>(in_proj_w, out_proj_w, w1, w2,
                                                    inpw, outpw, w1b, w2b);

  gemm_bt<0><<<dim3(3 * D_ / 128, MROWS / 128), 256, 0, stream>>>(
      hbuf, inpw, in_proj_b, nullptr, qkvb, nullptr, nullptr, vtb, MROWS, 3 * D_, D_);
  attn_kernel<<<dim3(B_ * H_, KTOK / 128), 256, 0, stream>>>(qkvb, vtb, obuf);
  gemm_bt<1><<<dim3(D_ / 128, MROWS / 128), 256, 0, stream>>>(
      obuf, outpw, out_proj_b, xs, nullptr, nullptr, nullptr, nullptr, MROWS, D_, D_);
  ln2_kernel<<<MROWS, 256, 0, stream>>>(xs, ln2g, ln2b, hbuf);
  gemm_ff1<<<dim3(4 * D_ / 256, MROWS / 256), 512, 0, stream>>>(
      hbuf, w1b, b1, ffb, MROWS, 4 * D_, D_);
  gemm_bt<3><<<dim3(D_ / 128, MROWS / 128), 256, 0, stream>>>(
      ffb, w2b, b2, xs, nullptr, out, idx, nullptr, MROWS, D_, 4 * D_);
}

// Round 5
// 713.461 us; speedup vs baseline: 1.1239x; 1.0357x over previous
//
#include <hip/hip_runtime.h>

#define B_    4
#define T_    4096
#define D_    1024
#define H_    16
#define DH_   64
#define KTOK  2048
#define MROWS (B_*KTOK)   // 8192

typedef unsigned short u16;
typedef __attribute__((ext_vector_type(8))) short short8;
typedef __attribute__((ext_vector_type(4))) float f32x4;
typedef __attribute__((ext_vector_type(4))) unsigned int u32x4;
typedef __attribute__((ext_vector_type(2))) unsigned int u32x2;
typedef __attribute__((ext_vector_type(4))) unsigned short u16x4;

static __device__ __forceinline__ u16 f2bf(float f) {
  union { float f; unsigned int u; } a; a.f = f;
  unsigned int u = a.u;
  unsigned int r = (u + 0x7FFFu + ((u >> 16) & 1u)) >> 16;   // RNE
  return (u16)r;
}

#if defined(__has_builtin)
#if __has_builtin(__builtin_amdgcn_exp2f)
#define EXP2F(x) __builtin_amdgcn_exp2f(x)
#endif
#endif
#ifndef EXP2F
#define EXP2F(x) exp2f(x)
#endif

// fast erf-based gelu: Abramowitz-Stegun 7.1.26, |err(erf)| < 2e-7 (vs bf16 ulp ~4e-3)
static __device__ __forceinline__ float gelu_f(float v) {
  float x = fabsf(v) * 0.70710678118654752f;
  float t = __builtin_amdgcn_rcpf(1.0f + 0.3275911f * x);
  float p = t * (0.254829592f + t * (-0.284496736f + t * (1.421413741f +
            t * (-1.453152027f + t * 1.061405429f))));
  float e = EXP2F(-1.4426950408889634f * x * x);
  float er = 1.0f - p * e;                    // erf(|x|)
  er = (v < 0.0f) ? -er : er;
  return 0.5f * v * (1.0f + er);
}

// pack two fp32 -> adjacent bf16 pair (low = a), TRUNCATING (1 v_perm).
static __device__ __forceinline__ unsigned int pkbf_t(float a, float b) {
  unsigned int ua = __builtin_bit_cast(unsigned int, a);
  unsigned int ub = __builtin_bit_cast(unsigned int, b);
  return __builtin_amdgcn_perm(ub, ua, 0x07060302u);  // [ua.hi16 low, ub.hi16 high]
}

static __device__ __forceinline__ void gld_lds16(const u16* g, u16* l) {
  __builtin_amdgcn_global_load_lds((__attribute__((address_space(1))) void*)g,
                                   (__attribute__((address_space(3))) void*)l, 16, 0, 0);
}

#define WAITV(N) asm volatile("s_waitcnt vmcnt(" #N ")" ::: "memory")

// ---------------- router: logits = x @ w_router, accumulate sum(logits^2) ----------------
__global__ void __launch_bounds__(256) router_kernel(const float* __restrict__ x,
    const float* __restrict__ wr, float* __restrict__ logits, float* __restrict__ auxacc)
{
  int tid = threadIdx.x; int lane = tid & 63, wave = tid >> 6;
  int row = blockIdx.x * 4 + wave;                 // 0 .. B*T-1
  const float* xr = x + (size_t)row * D_;
  float dot = 0.f;
#pragma unroll
  for (int j = 0; j < 4; j++) {
    int c = j * 256 + lane * 4;
    f32x4 xv = *(const f32x4*)(xr + c);
    f32x4 wv = *(const f32x4*)(wr + c);
    dot += xv[0]*wv[0] + xv[1]*wv[1] + xv[2]*wv[2] + xv[3]*wv[3];
  }
#pragma unroll
  for (int d = 1; d < 64; d <<= 1) dot += __shfl_xor(dot, d);
  __shared__ float red[4];
  if (lane == 0) { logits[row] = dot; red[wave] = dot; }
  __syncthreads();
  if (tid == 0) {
    float a = red[0]*red[0] + red[1]*red[1] + red[2]*red[2] + red[3]*red[3];
    atomicAdd(auxacc, a);
  }
}

// ---------------- rank: write RANK per token (rank<KTOK => selected, slot=rank) -----------
__global__ void __launch_bounds__(256) rank_kernel(const float* __restrict__ logits,
    int* __restrict__ rnk, int* __restrict__ idx,
    const float* __restrict__ acc, float* __restrict__ auxout)
{
  __shared__ float ll[T_];
  int b = blockIdx.y;
  int tid = threadIdx.x;
  if (b == 0 && blockIdx.x == 0 && tid == 0)
    auxout[0] = acc[0] * (0.01f / (float)(B_ * T_));
  const float* lg = logits + (size_t)b * T_;
  for (int j = tid; j < T_; j += 256) ll[j] = lg[j];
  __syncthreads();
  int t = blockIdx.x * 256 + tid;
  float my = ll[t];
  int rank = 0;
  for (int j = 0; j < T_; j += 4) {
    f32x4 lj = *(const f32x4*)&ll[j];
    rank += (lj[0] > my) || (lj[0] == my && (j+0) < t);
    rank += (lj[1] > my) || (lj[1] == my && (j+1) < t);
    rank += (lj[2] > my) || (lj[2] == my && (j+2) < t);
    rank += (lj[3] > my) || (lj[3] == my && (j+3) < t);
  }
  rnk[(size_t)b * T_ + t] = rank;
  if (rank < KTOK) idx[b * KTOK + rank] = t;
}

// ---------------- fused: pass-through unselected rows OR gather+LayerNorm selected --------
__global__ void __launch_bounds__(256) lnpass_kernel(const float* __restrict__ x,
    const int* __restrict__ rnk, const float* __restrict__ g, const float* __restrict__ bb,
    float* __restrict__ xs_out, u16* __restrict__ hout, float* __restrict__ out)
{
  int row = blockIdx.x;            // 0 .. B*T-1
  int tid = threadIdx.x;
  const float* srow = x + (size_t)row * D_;
  f32x4 v = *(const f32x4*)(srow + tid * 4);
  int r = rnk[row];
  if (r >= KTOK) {                 // unselected: copy x row to out (block-uniform branch)
    *(f32x4*)(out + (size_t)row * D_ + tid * 4) = v;
    return;
  }
  size_t mrow = (size_t)(row >> 12) * KTOK + r;   // T_=4096
  float s  = v[0] + v[1] + v[2] + v[3];
  float sq = v[0]*v[0] + v[1]*v[1] + v[2]*v[2] + v[3]*v[3];
#pragma unroll
  for (int d = 1; d < 64; d <<= 1) { s += __shfl_xor(s, d); sq += __shfl_xor(sq, d); }
  __shared__ float rs[4], rq[4];
  int lane = tid & 63, wave = tid >> 6;
  if (lane == 0) { rs[wave] = s; rq[wave] = sq; }
  __syncthreads();
  s  = rs[0] + rs[1] + rs[2] + rs[3];
  sq = rq[0] + rq[1] + rq[2] + rq[3];
  float mean = s * (1.0f / D_);
  float var  = sq * (1.0f / D_) - mean * mean;
  float rstd = rsqrtf(var + 1e-5f);
  f32x4 gg = *(const f32x4*)(g + tid * 4);
  f32x4 bv = *(const f32x4*)(bb + tid * 4);
  *(f32x4*)(xs_out + mrow * D_ + tid * 4) = v;
  u16x4 o;
#pragma unroll
  for (int j = 0; j < 4; j++) o[j] = f2bf((v[j] - mean) * rstd * gg[j] + bv[j]);
  *(u16x4*)(hout + mrow * D_ + tid * 4) = o;
}

// ---------------- LayerNorm (no gather) ----------------
__global__ void __launch_bounds__(256) ln2_kernel(const float* __restrict__ src,
    const float* __restrict__ g, const float* __restrict__ bb, u16* __restrict__ hout)
{
  int row = blockIdx.x;
  int tid = threadIdx.x;
  const float* srow = src + (size_t)row * D_;
  f32x4 v = *(const f32x4*)(srow + tid * 4);
  float s  = v[0] + v[1] + v[2] + v[3];
  float sq = v[0]*v[0] + v[1]*v[1] + v[2]*v[2] + v[3]*v[3];
#pragma unroll
  for (int d = 1; d < 64; d <<= 1) { s += __shfl_xor(s, d); sq += __shfl_xor(sq, d); }
  __shared__ float rs[4], rq[4];
  int lane = tid & 63, wave = tid >> 6;
  if (lane == 0) { rs[wave] = s; rq[wave] = sq; }
  __syncthreads();
  s  = rs[0] + rs[1] + rs[2] + rs[3];
  sq = rq[0] + rq[1] + rq[2] + rq[3];
  float mean = s * (1.0f / D_);
  float var  = sq * (1.0f / D_) - mean * mean;
  float rstd = rsqrtf(var + 1e-5f);
  f32x4 gg = *(const f32x4*)(g + tid * 4);
  f32x4 bv = *(const f32x4*)(bb + tid * 4);
  u16x4 o;
#pragma unroll
  for (int j = 0; j < 4; j++) o[j] = f2bf((v[j] - mean) * rstd * gg[j] + bv[j]);
  *(u16x4*)(hout + (size_t)row * D_ + tid * 4) = o;
}

// ---------------- fp32 -> bf16 convert, all 4 weight matrices in one dispatch ----------------
__global__ void __launch_bounds__(256) f2bf_all(const float* __restrict__ s0, const float* __restrict__ s1,
    const float* __restrict__ s2, const float* __restrict__ s3,
    u16* __restrict__ d0, u16* __restrict__ d1, u16* __restrict__ d2, u16* __restrict__ d3)
{
  const size_t c0 = (size_t)3 * D_ * D_, c1 = (size_t)4 * D_ * D_, c2 = (size_t)8 * D_ * D_;
  size_t e = (size_t)blockIdx.x * 1024 + (size_t)threadIdx.x * 4;
  const float* s; u16* d; size_t off;
  if (e < c0)      { s = s0; d = d0; off = e; }
  else if (e < c1) { s = s1; d = d1; off = e - c0; }
  else if (e < c2) { s = s2; d = d2; off = e - c1; }
  else             { s = s3; d = d3; off = e - c2; }
  f32x4 v = *(const f32x4*)(s + off);
  u16x4 o; o[0]=f2bf(v[0]); o[1]=f2bf(v[1]); o[2]=f2bf(v[2]); o[3]=f2bf(v[3]);
  *(u16x4*)(d + off) = o;
}

// ========== GEMM 128x128, BK=64, 4 row-waves, FF1-proven deep-prefetch schedule ===========
// Per K-tile: stage 4 pieces [Ar0,Ar1,B0,B1] of tile t+1 at TOP of tile t (8 loads/thread);
// 2 counted waits + 2 barriers per 32 MFMA/wave:
//   top: vmcnt(2) -> Ar0,Ar1,B0(t) done (issued a FULL TILE earlier); B1(t) in flight
//   mid: vmcnt(8) -> B1(t) done (the 8 t+1 loads in flight); never 0 in steady state
// Wave layout 4x1: wave owns rows wave*32..+31, all 128 cols. p0 = cols 0-63, p1 = 64-127.
// LDS 64KB -> 2 blocks/CU (cross-block overlap). Both-sides swizzle: src chunk (c^row)&7,
// linear dest, reads XOR same -> conflict-free. Accumulation order bitwise = old kernel.
// EPI 0: bf16 to Cb; Q cols pre-scaled; V cols transposed to vtb[bh][dh][tok]
// EPI 1: v += xs (fp32 residual), write fp32 to xs (in place)
// EPI 3: v += xs residual, scatter-write fp32 rows into outf at token idx
template<int EPI>
__global__ void __launch_bounds__(256, 2) gemm_bt(
    const u16* __restrict__ A, const u16* __restrict__ W,
    const float* __restrict__ bias, float* __restrict__ xs,
    u16* __restrict__ Cb, float* __restrict__ outf,
    const int* __restrict__ idx, u16* __restrict__ vtb, int M, int N, int K)
{
  __shared__ u16 As[2][128 * 64];
  __shared__ u16 Ws[2][128 * 64];
  const int tid = threadIdx.x;
  const int lane = tid & 63, wave = tid >> 6;
  const int m16 = lane & 15, quad = (lane >> 4) & 3;

  // chunked bijective XCD swizzle (grid divisible by 8)
  const int gx = gridDim.x;
  const int id = blockIdx.y * gx + blockIdx.x;
  const int cpx = (gx * (int)gridDim.y) >> 3;
  const int tl = (id & 7) * cpx + (id >> 3);
  const int bx = tl % gx, by = tl / gx;

  const size_t arow0 = (size_t)by * 128;
  const size_t wrow0 = (size_t)bx * 128;

  // stage one [64][64] u16 piece (8KB = 512 chunks), thread t -> chunks t, 256+t
  const int trow = tid >> 3;                // 0..31
  const int tcc  = (tid ^ trow) & 7;        // swizzled source col-chunk (inverse of read XOR)
  auto stagepc = [&](const u16* g0, u16* l0) {
    gld_lds16(g0 + (size_t)trow * K + tcc * 8,        l0 + (size_t)(tid & ~63) * 8);
    gld_lds16(g0 + (size_t)(32 + trow) * K + tcc * 8, l0 + 2048 + (size_t)(tid & ~63) * 8);
  };
  auto stage_tile = [&](int u, int s) {     // FIFO: Ar0, Ar1, B0, B1
    size_t kn = (size_t)u * 64;
    stagepc(A + (arow0)      * K + kn, &As[s][0]);
    stagepc(A + (arow0 + 64) * K + kn, &As[s][64 * 64]);
    stagepc(W + (wrow0)      * K + kn, &Ws[s][0]);
    stagepc(W + (wrow0 + 64) * K + kn, &Ws[s][64 * 64]);
  };

  auto ldA = [&](short8 (&f)[2][2], const u16* h) {
#pragma unroll
    for (int mt = 0; mt < 2; mt++) {
      int rr = wave * 32 + mt * 16 + m16;
      int sw = rr & 7;
#pragma unroll
      for (int kk = 0; kk < 2; kk++)
        f[mt][kk] = *(const short8*)&h[rr * 64 + (((kk * 4 + quad) ^ sw) * 8)];
    }
  };
  auto ldB = [&](short8 (&f)[4][2], const u16* h, int half) {
#pragma unroll
    for (int nt = 0; nt < 4; nt++) {
      int rb = half * 64 + nt * 16 + m16;
      int sw = rb & 7;
#pragma unroll
      for (int kk = 0; kk < 2; kk++)
        f[nt][kk] = *(const short8*)&h[rb * 64 + (((kk * 4 + quad) ^ sw) * 8)];
    }
  };

  f32x4 acc[2][8];
#pragma unroll
  for (int mt = 0; mt < 2; mt++)
#pragma unroll
    for (int n = 0; n < 8; n++) acc[mt][n] = (f32x4)0.0f;

  stage_tile(0, 0);

  const int NT = K >> 6;
  short8 af[2][2], bf[4][2], bf2[4][2];

  for (int t = 0; t < NT; t++) {
    const int cur = t & 1;
    const bool last = (t == NT - 1);

    WAITV(2);                                  // Ar0,Ar1,B0(t) done (issued full tile ago)
    __builtin_amdgcn_s_barrier();
    __builtin_amdgcn_sched_barrier(0);
    if (!last) stage_tile(t + 1, cur ^ 1);

    // p0: cols 0-63
    ldA(af, &As[cur][0]);
    ldB(bf, &Ws[cur][0], 0);
    __builtin_amdgcn_s_setprio(1);
#pragma unroll
    for (int mt = 0; mt < 2; mt++)
#pragma unroll
      for (int nt = 0; nt < 4; nt++)
#pragma unroll
        for (int kk = 0; kk < 2; kk++)
          acc[mt][nt] = __builtin_amdgcn_mfma_f32_16x16x32_bf16(af[mt][kk], bf[nt][kk], acc[mt][nt], 0, 0, 0);
    __builtin_amdgcn_s_setprio(0);

    if (last) { WAITV(0); } else { WAITV(8); } // B1(t) done; t+1's 8 loads stay in flight
    __builtin_amdgcn_s_barrier();
    __builtin_amdgcn_sched_barrier(0);

    // p1: cols 64-127 (barrier-free drift region)
    ldB(bf2, &Ws[cur][0], 1);
    __builtin_amdgcn_s_setprio(1);
#pragma unroll
    for (int mt = 0; mt < 2; mt++)
#pragma unroll
      for (int nt = 0; nt < 4; nt++)
#pragma unroll
        for (int kk = 0; kk < 2; kk++)
          acc[mt][4 + nt] = __builtin_amdgcn_mfma_f32_16x16x32_bf16(af[mt][kk], bf2[nt][kk], acc[mt][4 + nt], 0, 0, 0);
    __builtin_amdgcn_s_setprio(0);
  }

  // ---- epilogue ----
#pragma unroll
  for (int half = 0; half < 2; half++) {
#pragma unroll
    for (int mt = 0; mt < 2; mt++) {
#pragma unroll
      for (int nt = 0; nt < 4; nt++) {
        f32x4 a = acc[mt][half * 4 + nt];
        size_t col = wrow0 + half * 64 + nt * 16 + m16;
        float bvv = bias[col];
        size_t rowb = arow0 + wave * 32 + mt * 16 + quad * 4;
        if (EPI == 0) {
          if ((int)col < 2 * D_) {
            float sc = ((int)col < D_) ? 0.18033688f : 1.0f;  // fold 1/sqrt(dh)*log2(e) into Q
#pragma unroll
            for (int r = 0; r < 4; r++)
              Cb[(rowb + r) * (size_t)N + col] = f2bf((a[r] + bvv) * sc);
          } else {
            int hdh = (int)col - 2 * D_;
            int bb2 = (int)(rowb >> 11);
            int tok = (int)(rowb & (KTOK - 1));
            u16x4 o;
#pragma unroll
            for (int r = 0; r < 4; r++) o[r] = f2bf(a[r] + bvv);
            *(u16x4*)&vtb[(((size_t)(bb2 * H_) + (hdh >> 6)) * 64 + (hdh & 63)) * KTOK + tok] = o;
          }
        } else if (EPI == 1) {
#pragma unroll
          for (int r = 0; r < 4; r++) {
            size_t o = (rowb + r) * (size_t)N + col;
            xs[o] = xs[o] + (a[r] + bvv);
          }
        } else {
#pragma unroll
          for (int r = 0; r < 4; r++) {
            size_t row = rowb + r;
            int b = (int)(row >> 11);
            int i = (int)(row & (KTOK - 1));
            int t = idx[b * KTOK + i];
            float vv = xs[row * (size_t)D_ + col] + (a[r] + bvv);
            outf[((size_t)b * T_ + t) * D_ + col] = vv;
          }
        }
      }
    }
  }
}

// ================= FF1 GEMM: 256x256, BK=64, 512 threads, deep-prefetch schedule ===========
__global__ void __launch_bounds__(512, 1) gemm_ff1(
    const u16* __restrict__ A, const u16* __restrict__ W,
    const float* __restrict__ bias, u16* __restrict__ Cb, int M, int N, int K)
{
  __shared__ u16 Asm[2][2][128 * 64];
  __shared__ u16 Bsm[2][2][128 * 64];

  const int tid = threadIdx.x;
  const int lane = tid & 63;
  const int w = tid >> 6;                  // wave 0..7
  const int m16 = lane & 15, quad = (lane >> 4) & 3;
  const int rowA = (w >> 2) * 64;          // within A-half
  const int rowB = (w & 3) * 32;           // within B-half

  const int gx = gridDim.x;
  const int id = blockIdx.y * gx + blockIdx.x;
  const int cpx = (gx * (int)gridDim.y) >> 3;
  const int tl = (id & 7) * cpx + (id >> 3);
  const int bx = tl % gx, by = tl / gx;

  const int arow0 = by * 256;
  const int wcol0 = bx * 256;

  const int th8 = tid >> 3;
  const int ccs = (tid ^ th8) & 7;
  auto stage = [&](const u16* g0, u16* l0) {       // one 128x64 half-tile (16KB), 2 loads/thread
    gld_lds16(g0 + (size_t)th8 * K + ccs * 8,        l0 + (size_t)(tid & ~63) * 8);
    gld_lds16(g0 + (size_t)(64 + th8) * K + ccs * 8, l0 + 4096 + (size_t)(tid & ~63) * 8);
  };
  auto stage_tile = [&](int u, int s) {            // FIFO order: A0, B0, A1, B1
    size_t kn = (size_t)u * 64;
    stage(A + (size_t)arow0 * K + kn,         &Asm[s][0][0]);
    stage(W + (size_t)wcol0 * K + kn,         &Bsm[s][0][0]);
    stage(A + (size_t)(arow0 + 128) * K + kn, &Asm[s][1][0]);
    stage(W + (size_t)(wcol0 + 128) * K + kn, &Bsm[s][1][0]);
  };

  auto ldA = [&](short8 (&f)[4][2], const u16* h) {
#pragma unroll
    for (int mt = 0; mt < 4; mt++) {
      int rr = rowA + mt * 16 + m16;
      int sw = rr & 7;
#pragma unroll
      for (int kk = 0; kk < 2; kk++)
        f[mt][kk] = *(const short8*)&h[rr * 64 + (((kk * 4 + quad) ^ sw) * 8)];
    }
  };
  auto ldB = [&](short8 (&f)[2][2], const u16* h) {
#pragma unroll
    for (int nt = 0; nt < 2; nt++) {
      int rb = rowB + nt * 16 + m16;
      int sw = rb & 7;
#pragma unroll
      for (int kk = 0; kk < 2; kk++)
        f[nt][kk] = *(const short8*)&h[rb * 64 + (((kk * 4 + quad) ^ sw) * 8)];
    }
  };

  f32x4 acc[4][4][2];
#pragma unroll
  for (int q = 0; q < 4; q++)
#pragma unroll
    for (int mt = 0; mt < 4; mt++)
#pragma unroll
      for (int nt = 0; nt < 2; nt++) acc[q][mt][nt] = (f32x4)0.0f;

#define MMQ(QD, FA, FB) do { \
  __builtin_amdgcn_s_setprio(1); \
  _Pragma("unroll") for (int mt = 0; mt < 4; mt++) \
  _Pragma("unroll") for (int nt = 0; nt < 2; nt++) \
  _Pragma("unroll") for (int kk = 0; kk < 2; kk++) \
    acc[QD][mt][nt] = __builtin_amdgcn_mfma_f32_16x16x32_bf16(FA[mt][kk], FB[nt][kk], acc[QD][mt][nt], 0, 0, 0); \
  __builtin_amdgcn_s_setprio(0); } while (0)

  stage_tile(0, 0);

  const int NT = K >> 6;
  short8 af[4][2], af2[4][2], bf[2][2], bf2[2][2];

  for (int t = 0; t < NT; t++) {
    const int cur = t & 1;
    const bool last = (t == NT - 1);

    WAITV(4);                                   // A0,B0(t) done; A1,B1(t) may be in flight
    __builtin_amdgcn_s_barrier();
    __builtin_amdgcn_sched_barrier(0);
    if (!last) stage_tile(t + 1, cur ^ 1);      // 8 loads; slots freed by this barrier

    // p0: (A0,B0)
    ldA(af, &Asm[cur][0][0]);
    ldB(bf, &Bsm[cur][0][0]);
    MMQ(0, af, bf);

    if (last) { WAITV(0); } else { WAITV(8); }  // A1,B1(t) done; t+1's 8 loads in flight
    __builtin_amdgcn_s_barrier();
    __builtin_amdgcn_sched_barrier(0);

    // p1..p3: barrier-free drift region
    ldB(bf2, &Bsm[cur][1][0]);
    MMQ(1, af, bf2);
    ldA(af2, &Asm[cur][1][0]);
    MMQ(2, af2, bf);
    MMQ(3, af2, bf2);
  }
#undef MMQ

  // ---- epilogue: gelu(bf16) ----
#pragma unroll
  for (int qd = 0; qd < 4; qd++) {
    const int ha = qd >> 1, hb = qd & 1;
#pragma unroll
    for (int mt = 0; mt < 4; mt++) {
#pragma unroll
      for (int nt = 0; nt < 2; nt++) {
        f32x4 a = acc[qd][mt][nt];
        size_t col = (size_t)wcol0 + hb * 128 + (w & 3) * 32 + nt * 16 + m16;
        float bvv = bias[col];
        size_t rowb = (size_t)arow0 + ha * 128 + (w >> 2) * 64 + mt * 16 + quad * 4;
#pragma unroll
        for (int r = 0; r < 4; r++)
          Cb[(rowb + r) * (size_t)N + col] = f2bf(gelu_f(a[r] + bvv));
      }
    }
  }
}

// ---------------- flash attention: dual-Ps (per-qh buffer) breaks the serial qh chain ------
#define PSTR 72
__global__ void __launch_bounds__(256, 3) attn_kernel(const u16* __restrict__ qkv,
                                                      const u16* __restrict__ vtb,
                                                      u16* __restrict__ obuf)
{
  __shared__ u16 Ks[2][64 * 64];        // 2 x 8192 B
  __shared__ u16 Vs[2][64 * 64];        // 2 x 8192 B
  __shared__ u16 Ps[4][2][16 * PSTR];   // 18432 B        total 50 KB -> 3 blocks/CU

  const int tid = threadIdx.x;
  const int lane = tid & 63, wave = tid >> 6;
  const int m16 = lane & 15, quad = lane >> 4;
  const int bh = blockIdx.x;
  const int b = bh >> 4, h = bh & 15;
  const int q0 = blockIdx.y * 128 + wave * 32;     // this wave: q0..q0+31

  const u16* base = qkv + ((size_t)b * KTOK) * (3 * D_) + h * DH_;
  const u16* vb   = vtb + (size_t)bh * 64 * KTOK;  // rows = dh, stride KTOK

  short8 qf[2][2];
#pragma unroll
  for (int qh = 0; qh < 2; qh++) {
    const u16* qrow = base + (size_t)(q0 + qh * 16 + m16) * (3 * D_);
    qf[qh][0] = *(const short8*)(qrow + quad * 8);
    qf[qh][1] = *(const short8*)(qrow + 32 + quad * 8);
  }

  f32x4 oacc[2][4];
#pragma unroll
  for (int qh = 0; qh < 2; qh++)
#pragma unroll
    for (int nt = 0; nt < 4; nt++) oacc[qh][nt] = (f32x4)0.0f;
  f32x4 lsum[2] = {(f32x4)0.0f, (f32x4)0.0f};

  auto stage_tile = [&](const u16* g0, size_t rstride, u16* lds) {
#pragma unroll
    for (int c = 0; c < 2; c++) {
      int g = c * 256 + tid;
      int key = g >> 3;
      int cc = (g ^ key) & 7;
      gld_lds16(g0 + (size_t)key * rstride + cc * 8,
                lds + (size_t)(c * 256 + (tid & ~63)) * 8);
    }
  };

  stage_tile(base + D_, 3 * D_, &Ks[0][0]);
  stage_tile(vb, KTOK, &Vs[0][0]);
  __syncthreads();

  int buf = 0;
  for (int tk = 0; tk < KTOK; tk += 64) {
    if (tk + 64 < KTOK) {
      stage_tile(base + (size_t)(tk + 64) * (3 * D_) + D_, 3 * D_, &Ks[buf ^ 1][0]);
      stage_tile(vb + (tk + 64), KTOK, &Vs[buf ^ 1][0]);
    }
    const u16* Kb = &Ks[buf][0];
    const u16* Vb = &Vs[buf][0];

    // ---- S^T = K Q^T ----
    f32x4 sacc[2][4];
#pragma unroll
    for (int qh = 0; qh < 2; qh++)
#pragma unroll
      for (int nt = 0; nt < 4; nt++) sacc[qh][nt] = (f32x4)0.0f;
    __builtin_amdgcn_s_setprio(1);
#pragma unroll
    for (int nt = 0; nt < 4; nt++) {
      int row = nt * 16 + m16;
      int sw = row & 7;
      short8 kf0 = *(const short8*)&Kb[row * 64 + ((quad ^ sw) * 8)];
      short8 kf1 = *(const short8*)&Kb[row * 64 + (((4 + quad) ^ sw) * 8)];
#pragma unroll
      for (int qh = 0; qh < 2; qh++) {
        sacc[qh][nt] = __builtin_amdgcn_mfma_f32_16x16x32_bf16(kf0, qf[qh][0], sacc[qh][nt], 0, 0, 0);
        sacc[qh][nt] = __builtin_amdgcn_mfma_f32_16x16x32_bf16(kf1, qf[qh][1], sacc[qh][nt], 0, 0, 0);
      }
    }
    __builtin_amdgcn_s_setprio(0);

    // ---- hoisted V B-fragments ----
    short8 vf[4][2];
#pragma unroll
    for (int nt = 0; nt < 4; nt++) {
      int row = nt * 16 + m16;
      int sw = row & 7;
      vf[nt][0] = *(const short8*)&Vb[row * 64 + ((quad ^ sw) * 8)];
      vf[nt][1] = *(const short8*)&Vb[row * 64 + (((4 + quad) ^ sw) * 8)];
    }

    // ---- exp2 + pack + store BOTH qh (independent buffers -> no LDS aliasing hazard) ----
#pragma unroll
    for (int qh = 0; qh < 2; qh++) {
#pragma unroll
      for (int nt = 0; nt < 4; nt++) {
        f32x4 p;
#pragma unroll
        for (int r = 0; r < 4; r++) p[r] = EXP2F(sacc[qh][nt][r]);
        lsum[qh] += p;
        u32x2 w2; w2[0] = pkbf_t(p[0], p[1]); w2[1] = pkbf_t(p[2], p[3]);
        *(u32x2*)&Ps[wave][qh][m16 * PSTR + nt * 16 + quad * 4] = w2;
      }
    }
    // ---- read P A-frags for both qh, then one 16-MFMA PV cluster ----
    short8 pa[2][2];
#pragma unroll
    for (int qh = 0; qh < 2; qh++) {
      pa[qh][0] = *(const short8*)&Ps[wave][qh][m16 * PSTR + quad * 8];
      pa[qh][1] = *(const short8*)&Ps[wave][qh][m16 * PSTR + 32 + quad * 8];
    }
    __builtin_amdgcn_s_setprio(1);
#pragma unroll
    for (int qh = 0; qh < 2; qh++)
#pragma unroll
      for (int nt = 0; nt < 4; nt++) {
        oacc[qh][nt] = __builtin_amdgcn_mfma_f32_16x16x32_bf16(pa[qh][0], vf[nt][0], oacc[qh][nt], 0, 0, 0);
        oacc[qh][nt] = __builtin_amdgcn_mfma_f32_16x16x32_bf16(pa[qh][1], vf[nt][1], oacc[qh][nt], 0, 0, 0);
      }
    __builtin_amdgcn_s_setprio(0);

    __syncthreads();
    buf ^= 1;
  }

  float rl[2][4];
#pragma unroll
  for (int qh = 0; qh < 2; qh++) {
    float l = (lsum[qh][0] + lsum[qh][1]) + (lsum[qh][2] + lsum[qh][3]);
    l += __shfl_xor(l, 16);
    l += __shfl_xor(l, 32);
#pragma unroll
    for (int r = 0; r < 4; r++) {
      float lr = __shfl(l, (lane & 48) | (quad * 4 + r));
      rl[qh][r] = 1.0f / lr;
    }
  }

#pragma unroll
  for (int qh = 0; qh < 2; qh++)
#pragma unroll
    for (int nt = 0; nt < 4; nt++)
#pragma unroll
      for (int r = 0; r < 4; r++) {
        int qq = q0 + qh * 16 + quad * 4 + r;
        float v = oacc[qh][nt][r] * rl[qh][r];
        obuf[((size_t)b * KTOK + qq) * D_ + h * DH_ + nt * 16 + m16] = f2bf(v);
      }
}

// ---------------- launch ----------------
extern "C" void kernel_launch(void* const* d_in, const int* in_sizes, int n_in,
                              void* d_out, int out_size, void* d_ws, size_t ws_size,
                              hipStream_t stream)
{
  (void)in_sizes; (void)n_in; (void)out_size; (void)ws_size;
  const float* x          = (const float*)d_in[0];
  const float* w_router   = (const float*)d_in[1];
  const float* in_proj_w  = (const float*)d_in[2];
  const float* in_proj_b  = (const float*)d_in[3];
  const float* out_proj_w = (const float*)d_in[4];
  const float* out_proj_b = (const float*)d_in[5];
  const float* w1         = (const float*)d_in[6];
  const float* b1         = (const float*)d_in[7];
  const float* w2         = (const float*)d_in[8];
  const float* b2         = (const float*)d_in[9];
  const float* ln1g       = (const float*)d_in[10];
  const float* ln1b       = (const float*)d_in[11];
  const float* ln2g       = (const float*)d_in[12];
  const float* ln2b       = (const float*)d_in[13];
  float* out = (float*)d_out;

  char* w = (char*)d_ws;
  auto alloc = [&](size_t bytes) -> char* {
    char* p = w; w += (bytes + 255) & ~(size_t)255; return p;
  };
  float* logits = (float*)alloc((size_t)B_ * T_ * 4);
  int*   rnk    = (int*)  alloc((size_t)B_ * T_ * 4);
  int*   idx    = (int*)  alloc((size_t)B_ * KTOK * 4);
  float* auxacc = (float*)alloc(256);
  u16* inpw  = (u16*)alloc((size_t)3 * D_ * D_ * 2);
  u16* outpw = (u16*)alloc((size_t)D_ * D_ * 2);
  u16* w1b   = (u16*)alloc((size_t)4 * D_ * D_ * 2);
  u16* w2b   = (u16*)alloc((size_t)4 * D_ * D_ * 2);
  float* xs  = (float*)alloc((size_t)MROWS * D_ * 4);
  u16* hbuf  = (u16*)alloc((size_t)MROWS * D_ * 2);
  char* region = alloc((size_t)MROWS * 4 * D_ * 2);      // 64 MB: qkv(48)+obuf(16), reused by ff
  u16* qkvb = (u16*)region;
  u16* obuf = (u16*)(region + (size_t)MROWS * 3 * D_ * 2);
  u16* ffb  = (u16*)region;
  u16* vtb  = (u16*)alloc((size_t)B_ * H_ * DH_ * KTOK * 2);   // 16 MB: V transposed [bh][dh][tok]

  (void)hipMemsetAsync(auxacc, 0, 4, stream);

  router_kernel<<<B_ * T_ / 4, 256, 0, stream>>>(x, w_router, logits, auxacc);
  rank_kernel<<<dim3(T_ / 256, B_), 256, 0, stream>>>(logits, rnk, idx, auxacc,
                                                      out + (size_t)B_ * T_ * D_);
  lnpass_kernel<<<B_ * T_, 256, 0, stream>>>(x, rnk, ln1g, ln1b, xs, hbuf, out);

  f2bf_all<<<12 * D_ * D_ / 1024, 256, 0, stream>>>(in_proj_w, out_proj_w, w1, w2,
                                                    inpw, outpw, w1b, w2b);

  gemm_bt<0><<<dim3(3 * D_ / 128, MROWS / 128), 256, 0, stream>>>(
      hbuf, inpw, in_proj_b, nullptr, qkvb, nullptr, nullptr, vtb, MROWS, 3 * D_, D_);
  attn_kernel<<<dim3(B_ * H_, KTOK / 128), 256, 0, stream>>>(qkvb, vtb, obuf);
  gemm_bt<1><<<dim3(D_ / 128, MROWS / 128), 256, 0, stream>>>(
      obuf, outpw, out_proj_b, xs, nullptr, nullptr, nullptr, nullptr, MROWS, D_, D_);
  ln2_kernel<<<MROWS, 256, 0, stream>>>(xs, ln2g, ln2b, hbuf);
  gemm_ff1<<<dim3(4 * D_ / 256, MROWS / 256), 512, 0, stream>>>(
      hbuf, w1b, b1, ffb, MROWS, 4 * D_, D_);
  gemm_bt<3><<<dim3(D_ / 128, MROWS / 128), 256, 0, stream>>>(
      ffb, w2b, b2, xs, nullptr, out, idx, nullptr, MROWS, D_, 4 * D_);
}

// Round 6
// 626.138 us; speedup vs baseline: 1.2806x; 1.1395x over previous
//
#include <hip/hip_runtime.h>

#define B_    4
#define T_    4096
#define D_    1024
#define H_    16
#define DH_   64
#define KTOK  2048
#define MROWS (B_*KTOK)   // 8192

typedef unsigned short u16;
typedef __attribute__((ext_vector_type(8))) short short8;
typedef __attribute__((ext_vector_type(4))) float f32x4;
typedef __attribute__((ext_vector_type(4))) unsigned int u32x4;
typedef __attribute__((ext_vector_type(2))) unsigned int u32x2;
typedef __attribute__((ext_vector_type(4))) unsigned short u16x4;

static __device__ __forceinline__ u16 f2bf(float f) {
  union { float f; unsigned int u; } a; a.f = f;
  unsigned int u = a.u;
  unsigned int r = (u + 0x7FFFu + ((u >> 16) & 1u)) >> 16;   // RNE
  return (u16)r;
}

#if defined(__has_builtin)
#if __has_builtin(__builtin_amdgcn_exp2f)
#define EXP2F(x) __builtin_amdgcn_exp2f(x)
#endif
#endif
#ifndef EXP2F
#define EXP2F(x) exp2f(x)
#endif

// fast erf-based gelu: Abramowitz-Stegun 7.1.26, |err(erf)| < 2e-7 (vs bf16 ulp ~4e-3)
static __device__ __forceinline__ float gelu_f(float v) {
  float x = fabsf(v) * 0.70710678118654752f;
  float t = __builtin_amdgcn_rcpf(1.0f + 0.3275911f * x);
  float p = t * (0.254829592f + t * (-0.284496736f + t * (1.421413741f +
            t * (-1.453152027f + t * 1.061405429f))));
  float e = EXP2F(-1.4426950408889634f * x * x);
  float er = 1.0f - p * e;                    // erf(|x|)
  er = (v < 0.0f) ? -er : er;
  return 0.5f * v * (1.0f + er);
}

// pack two fp32 -> adjacent bf16 pair (low = a), TRUNCATING (1 v_perm).
static __device__ __forceinline__ unsigned int pkbf_t(float a, float b) {
  unsigned int ua = __builtin_bit_cast(unsigned int, a);
  unsigned int ub = __builtin_bit_cast(unsigned int, b);
  return __builtin_amdgcn_perm(ub, ua, 0x07060302u);  // [ua.hi16 low, ub.hi16 high]
}

static __device__ __forceinline__ void gld_lds16(const u16* g, u16* l) {
  __builtin_amdgcn_global_load_lds((__attribute__((address_space(1))) void*)g,
                                   (__attribute__((address_space(3))) void*)l, 16, 0, 0);
}

#define WAITV(N) asm volatile("s_waitcnt vmcnt(" #N ")" ::: "memory")

// ---------------- router: logits = x @ w_router, accumulate sum(logits^2) ----------------
__global__ void __launch_bounds__(256) router_kernel(const float* __restrict__ x,
    const float* __restrict__ wr, float* __restrict__ logits, float* __restrict__ auxacc)
{
  int tid = threadIdx.x; int lane = tid & 63, wave = tid >> 6;
  int row = blockIdx.x * 4 + wave;                 // 0 .. B*T-1
  const float* xr = x + (size_t)row * D_;
  float dot = 0.f;
#pragma unroll
  for (int j = 0; j < 4; j++) {
    int c = j * 256 + lane * 4;
    f32x4 xv = *(const f32x4*)(xr + c);
    f32x4 wv = *(const f32x4*)(wr + c);
    dot += xv[0]*wv[0] + xv[1]*wv[1] + xv[2]*wv[2] + xv[3]*wv[3];
  }
#pragma unroll
  for (int d = 1; d < 64; d <<= 1) dot += __shfl_xor(dot, d);
  __shared__ float red[4];
  if (lane == 0) { logits[row] = dot; red[wave] = dot; }
  __syncthreads();
  if (tid == 0) {
    float a = red[0]*red[0] + red[1]*red[1] + red[2]*red[2] + red[3]*red[3];
    atomicAdd(auxacc, a);
  }
}

// -------- partial rank: grid (T/256, B, 16 chunks); atomicAdd partial counts into rnk ------
// Old single-pass rank was 101 µs: 64 blocks = 1 wave/SIMD, 1024-iter serial ds_read chain
// (latency-bound at ~120cy/read). 1024 blocks + 4-deep unroll hides the latency; rank
// semantics (strict-greater + index tie-break) sum exactly across chunks.
__global__ void __launch_bounds__(256) rankp_kernel(const float* __restrict__ logits,
    int* __restrict__ rnk)
{
  __shared__ float ll[256];
  const int b = blockIdx.y, ch = blockIdx.z;
  const int tid = threadIdx.x;
  const float* lg = logits + (size_t)b * T_;
  const int j0 = ch * 256;
  ll[tid] = lg[j0 + tid];
  __syncthreads();
  const int t = blockIdx.x * 256 + tid;
  const float my = lg[t];
  int rank = 0;
#pragma unroll 4
  for (int j = 0; j < 256; j += 4) {
    f32x4 lj = *(const f32x4*)&ll[j];
    int jg = j0 + j;
    rank += (lj[0] > my) || (lj[0] == my && (jg+0) < t);
    rank += (lj[1] > my) || (lj[1] == my && (jg+1) < t);
    rank += (lj[2] > my) || (lj[2] == my && (jg+2) < t);
    rank += (lj[3] > my) || (lj[3] == my && (jg+3) < t);
  }
  atomicAdd(&rnk[(size_t)b * T_ + t], rank);
}

// ---------------- fused: pass-through unselected OR gather+LN selected; builds idx --------
__global__ void __launch_bounds__(256) lnpass_kernel(const float* __restrict__ x,
    const int* __restrict__ rnk, const float* __restrict__ g, const float* __restrict__ bb,
    float* __restrict__ xs_out, u16* __restrict__ hout, float* __restrict__ out,
    int* __restrict__ idx, const float* __restrict__ acc, float* __restrict__ auxout)
{
  int row = blockIdx.x;            // 0 .. B*T-1
  int tid = threadIdx.x;
  if (row == 0 && tid == 0) auxout[0] = acc[0] * (0.01f / (float)(B_ * T_));
  const float* srow = x + (size_t)row * D_;
  f32x4 v = *(const f32x4*)(srow + tid * 4);
  int r = rnk[row];                // block-uniform
  if (r >= KTOK) {                 // unselected: copy x row to out
    *(f32x4*)(out + (size_t)row * D_ + tid * 4) = v;
    return;
  }
  if (tid == 0) idx[(row >> 12) * KTOK + r] = row & (T_ - 1);   // T_=4096
  size_t mrow = (size_t)(row >> 12) * KTOK + r;
  float s  = v[0] + v[1] + v[2] + v[3];
  float sq = v[0]*v[0] + v[1]*v[1] + v[2]*v[2] + v[3]*v[3];
#pragma unroll
  for (int d = 1; d < 64; d <<= 1) { s += __shfl_xor(s, d); sq += __shfl_xor(sq, d); }
  __shared__ float rs[4], rq[4];
  int lane = tid & 63, wave = tid >> 6;
  if (lane == 0) { rs[wave] = s; rq[wave] = sq; }
  __syncthreads();
  s  = rs[0] + rs[1] + rs[2] + rs[3];
  sq = rq[0] + rq[1] + rq[2] + rq[3];
  float mean = s * (1.0f / D_);
  float var  = sq * (1.0f / D_) - mean * mean;
  float rstd = rsqrtf(var + 1e-5f);
  f32x4 gg = *(const f32x4*)(g + tid * 4);
  f32x4 bv = *(const f32x4*)(bb + tid * 4);
  *(f32x4*)(xs_out + mrow * D_ + tid * 4) = v;
  u16x4 o;
#pragma unroll
  for (int j = 0; j < 4; j++) o[j] = f2bf((v[j] - mean) * rstd * gg[j] + bv[j]);
  *(u16x4*)(hout + mrow * D_ + tid * 4) = o;
}

// ---------------- LayerNorm (no gather) ----------------
__global__ void __launch_bounds__(256) ln2_kernel(const float* __restrict__ src,
    const float* __restrict__ g, const float* __restrict__ bb, u16* __restrict__ hout)
{
  int row = blockIdx.x;
  int tid = threadIdx.x;
  const float* srow = src + (size_t)row * D_;
  f32x4 v = *(const f32x4*)(srow + tid * 4);
  float s  = v[0] + v[1] + v[2] + v[3];
  float sq = v[0]*v[0] + v[1]*v[1] + v[2]*v[2] + v[3]*v[3];
#pragma unroll
  for (int d = 1; d < 64; d <<= 1) { s += __shfl_xor(s, d); sq += __shfl_xor(sq, d); }
  __shared__ float rs[4], rq[4];
  int lane = tid & 63, wave = tid >> 6;
  if (lane == 0) { rs[wave] = s; rq[wave] = sq; }
  __syncthreads();
  s  = rs[0] + rs[1] + rs[2] + rs[3];
  sq = rq[0] + rq[1] + rq[2] + rq[3];
  float mean = s * (1.0f / D_);
  float var  = sq * (1.0f / D_) - mean * mean;
  float rstd = rsqrtf(var + 1e-5f);
  f32x4 gg = *(const f32x4*)(g + tid * 4);
  f32x4 bv = *(const f32x4*)(bb + tid * 4);
  u16x4 o;
#pragma unroll
  for (int j = 0; j < 4; j++) o[j] = f2bf((v[j] - mean) * rstd * gg[j] + bv[j]);
  *(u16x4*)(hout + (size_t)row * D_ + tid * 4) = o;
}

// ---------------- fp32 -> bf16 convert, all 4 weight matrices in one dispatch ----------------
__global__ void __launch_bounds__(256) f2bf_all(const float* __restrict__ s0, const float* __restrict__ s1,
    const float* __restrict__ s2, const float* __restrict__ s3,
    u16* __restrict__ d0, u16* __restrict__ d1, u16* __restrict__ d2, u16* __restrict__ d3)
{
  const size_t c0 = (size_t)3 * D_ * D_, c1 = (size_t)4 * D_ * D_, c2 = (size_t)8 * D_ * D_;
  size_t e = (size_t)blockIdx.x * 1024 + (size_t)threadIdx.x * 4;
  const float* s; u16* d; size_t off;
  if (e < c0)      { s = s0; d = d0; off = e; }
  else if (e < c1) { s = s1; d = d1; off = e - c0; }
  else if (e < c2) { s = s2; d = d2; off = e - c1; }
  else             { s = s3; d = d3; off = e - c2; }
  f32x4 v = *(const f32x4*)(s + off);
  u16x4 o; o[0]=f2bf(v[0]); o[1]=f2bf(v[1]); o[2]=f2bf(v[2]); o[3]=f2bf(v[3]);
  *(u16x4*)(d + off) = o;
}

// ========== GEMM 128x128, BK=64, 4 row-waves, deep-prefetch schedule (round-5 proven) ======
template<int EPI>
__global__ void __launch_bounds__(256, 2) gemm_bt(
    const u16* __restrict__ A, const u16* __restrict__ W,
    const float* __restrict__ bias, float* __restrict__ xs,
    u16* __restrict__ Cb, float* __restrict__ outf,
    const int* __restrict__ idx, u16* __restrict__ vtb, int M, int N, int K)
{
  __shared__ u16 As[2][128 * 64];
  __shared__ u16 Ws[2][128 * 64];
  const int tid = threadIdx.x;
  const int lane = tid & 63, wave = tid >> 6;
  const int m16 = lane & 15, quad = (lane >> 4) & 3;

  // chunked bijective XCD swizzle (grid divisible by 8)
  const int gx = gridDim.x;
  const int id = blockIdx.y * gx + blockIdx.x;
  const int cpx = (gx * (int)gridDim.y) >> 3;
  const int tl = (id & 7) * cpx + (id >> 3);
  const int bx = tl % gx, by = tl / gx;

  const size_t arow0 = (size_t)by * 128;
  const size_t wrow0 = (size_t)bx * 128;

  // stage one [64][64] u16 piece (8KB = 512 chunks), thread t -> chunks t, 256+t
  const int trow = tid >> 3;                // 0..31
  const int tcc  = (tid ^ trow) & 7;        // swizzled source col-chunk (inverse of read XOR)
  auto stagepc = [&](const u16* g0, u16* l0) {
    gld_lds16(g0 + (size_t)trow * K + tcc * 8,        l0 + (size_t)(tid & ~63) * 8);
    gld_lds16(g0 + (size_t)(32 + trow) * K + tcc * 8, l0 + 2048 + (size_t)(tid & ~63) * 8);
  };
  auto stage_tile = [&](int u, int s) {     // FIFO: Ar0, Ar1, B0, B1
    size_t kn = (size_t)u * 64;
    stagepc(A + (arow0)      * K + kn, &As[s][0]);
    stagepc(A + (arow0 + 64) * K + kn, &As[s][64 * 64]);
    stagepc(W + (wrow0)      * K + kn, &Ws[s][0]);
    stagepc(W + (wrow0 + 64) * K + kn, &Ws[s][64 * 64]);
  };

  auto ldA = [&](short8 (&f)[2][2], const u16* h) {
#pragma unroll
    for (int mt = 0; mt < 2; mt++) {
      int rr = wave * 32 + mt * 16 + m16;
      int sw = rr & 7;
#pragma unroll
      for (int kk = 0; kk < 2; kk++)
        f[mt][kk] = *(const short8*)&h[rr * 64 + (((kk * 4 + quad) ^ sw) * 8)];
    }
  };
  auto ldB = [&](short8 (&f)[4][2], const u16* h, int half) {
#pragma unroll
    for (int nt = 0; nt < 4; nt++) {
      int rb = half * 64 + nt * 16 + m16;
      int sw = rb & 7;
#pragma unroll
      for (int kk = 0; kk < 2; kk++)
        f[nt][kk] = *(const short8*)&h[rb * 64 + (((kk * 4 + quad) ^ sw) * 8)];
    }
  };

  f32x4 acc[2][8];
#pragma unroll
  for (int mt = 0; mt < 2; mt++)
#pragma unroll
    for (int n = 0; n < 8; n++) acc[mt][n] = (f32x4)0.0f;

  stage_tile(0, 0);

  const int NT = K >> 6;
  short8 af[2][2], bf[4][2], bf2[4][2];

  for (int t = 0; t < NT; t++) {
    const int cur = t & 1;
    const bool last = (t == NT - 1);

    WAITV(2);                                  // Ar0,Ar1,B0(t) done (issued full tile ago)
    __builtin_amdgcn_s_barrier();
    __builtin_amdgcn_sched_barrier(0);
    if (!last) stage_tile(t + 1, cur ^ 1);

    // p0: cols 0-63
    ldA(af, &As[cur][0]);
    ldB(bf, &Ws[cur][0], 0);
    __builtin_amdgcn_s_setprio(1);
#pragma unroll
    for (int mt = 0; mt < 2; mt++)
#pragma unroll
      for (int nt = 0; nt < 4; nt++)
#pragma unroll
        for (int kk = 0; kk < 2; kk++)
          acc[mt][nt] = __builtin_amdgcn_mfma_f32_16x16x32_bf16(af[mt][kk], bf[nt][kk], acc[mt][nt], 0, 0, 0);
    __builtin_amdgcn_s_setprio(0);

    if (last) { WAITV(0); } else { WAITV(8); } // B1(t) done; t+1's 8 loads stay in flight
    __builtin_amdgcn_s_barrier();
    __builtin_amdgcn_sched_barrier(0);

    // p1: cols 64-127 (barrier-free drift region)
    ldB(bf2, &Ws[cur][0], 1);
    __builtin_amdgcn_s_setprio(1);
#pragma unroll
    for (int mt = 0; mt < 2; mt++)
#pragma unroll
      for (int nt = 0; nt < 4; nt++)
#pragma unroll
        for (int kk = 0; kk < 2; kk++)
          acc[mt][4 + nt] = __builtin_amdgcn_mfma_f32_16x16x32_bf16(af[mt][kk], bf2[nt][kk], acc[mt][4 + nt], 0, 0, 0);
    __builtin_amdgcn_s_setprio(0);
  }

  // ---- epilogue ----
#pragma unroll
  for (int half = 0; half < 2; half++) {
#pragma unroll
    for (int mt = 0; mt < 2; mt++) {
#pragma unroll
      for (int nt = 0; nt < 4; nt++) {
        f32x4 a = acc[mt][half * 4 + nt];
        size_t col = wrow0 + half * 64 + nt * 16 + m16;
        float bvv = bias[col];
        size_t rowb = arow0 + wave * 32 + mt * 16 + quad * 4;
        if (EPI == 0) {
          if ((int)col < 2 * D_) {
            float sc = ((int)col < D_) ? 0.18033688f : 1.0f;  // fold 1/sqrt(dh)*log2(e) into Q
#pragma unroll
            for (int r = 0; r < 4; r++)
              Cb[(rowb + r) * (size_t)N + col] = f2bf((a[r] + bvv) * sc);
          } else {
            int hdh = (int)col - 2 * D_;
            int bb2 = (int)(rowb >> 11);
            int tok = (int)(rowb & (KTOK - 1));
            u16x4 o;
#pragma unroll
            for (int r = 0; r < 4; r++) o[r] = f2bf(a[r] + bvv);
            *(u16x4*)&vtb[(((size_t)(bb2 * H_) + (hdh >> 6)) * 64 + (hdh & 63)) * KTOK + tok] = o;
          }
        } else if (EPI == 1) {
#pragma unroll
          for (int r = 0; r < 4; r++) {
            size_t o = (rowb + r) * (size_t)N + col;
            xs[o] = xs[o] + (a[r] + bvv);
          }
        } else {
#pragma unroll
          for (int r = 0; r < 4; r++) {
            size_t row = rowb + r;
            int b = (int)(row >> 11);
            int i = (int)(row & (KTOK - 1));
            int t = idx[b * KTOK + i];
            float vv = xs[row * (size_t)D_ + col] + (a[r] + bvv);
            outf[((size_t)b * T_ + t) * D_ + col] = vv;
          }
        }
      }
    }
  }
}

// ================= FF1 GEMM: 256x256, BK=64, 512 threads, deep-prefetch schedule ===========
__global__ void __launch_bounds__(512, 1) gemm_ff1(
    const u16* __restrict__ A, const u16* __restrict__ W,
    const float* __restrict__ bias, u16* __restrict__ Cb, int M, int N, int K)
{
  __shared__ u16 Asm[2][2][128 * 64];
  __shared__ u16 Bsm[2][2][128 * 64];

  const int tid = threadIdx.x;
  const int lane = tid & 63;
  const int w = tid >> 6;                  // wave 0..7
  const int m16 = lane & 15, quad = (lane >> 4) & 3;
  const int rowA = (w >> 2) * 64;          // within A-half
  const int rowB = (w & 3) * 32;           // within B-half

  const int gx = gridDim.x;
  const int id = blockIdx.y * gx + blockIdx.x;
  const int cpx = (gx * (int)gridDim.y) >> 3;
  const int tl = (id & 7) * cpx + (id >> 3);
  const int bx = tl % gx, by = tl / gx;

  const int arow0 = by * 256;
  const int wcol0 = bx * 256;

  const int th8 = tid >> 3;
  const int ccs = (tid ^ th8) & 7;
  auto stage = [&](const u16* g0, u16* l0) {       // one 128x64 half-tile (16KB), 2 loads/thread
    gld_lds16(g0 + (size_t)th8 * K + ccs * 8,        l0 + (size_t)(tid & ~63) * 8);
    gld_lds16(g0 + (size_t)(64 + th8) * K + ccs * 8, l0 + 4096 + (size_t)(tid & ~63) * 8);
  };
  auto stage_tile = [&](int u, int s) {            // FIFO order: A0, B0, A1, B1
    size_t kn = (size_t)u * 64;
    stage(A + (size_t)arow0 * K + kn,         &Asm[s][0][0]);
    stage(W + (size_t)wcol0 * K + kn,         &Bsm[s][0][0]);
    stage(A + (size_t)(arow0 + 128) * K + kn, &Asm[s][1][0]);
    stage(W + (size_t)(wcol0 + 128) * K + kn, &Bsm[s][1][0]);
  };

  auto ldA = [&](short8 (&f)[4][2], const u16* h) {
#pragma unroll
    for (int mt = 0; mt < 4; mt++) {
      int rr = rowA + mt * 16 + m16;
      int sw = rr & 7;
#pragma unroll
      for (int kk = 0; kk < 2; kk++)
        f[mt][kk] = *(const short8*)&h[rr * 64 + (((kk * 4 + quad) ^ sw) * 8)];
    }
  };
  auto ldB = [&](short8 (&f)[2][2], const u16* h) {
#pragma unroll
    for (int nt = 0; nt < 2; nt++) {
      int rb = rowB + nt * 16 + m16;
      int sw = rb & 7;
#pragma unroll
      for (int kk = 0; kk < 2; kk++)
        f[nt][kk] = *(const short8*)&h[rb * 64 + (((kk * 4 + quad) ^ sw) * 8)];
    }
  };

  f32x4 acc[4][4][2];
#pragma unroll
  for (int q = 0; q < 4; q++)
#pragma unroll
    for (int mt = 0; mt < 4; mt++)
#pragma unroll
      for (int nt = 0; nt < 2; nt++) acc[q][mt][nt] = (f32x4)0.0f;

#define MMQ(QD, FA, FB) do { \
  __builtin_amdgcn_s_setprio(1); \
  _Pragma("unroll") for (int mt = 0; mt < 4; mt++) \
  _Pragma("unroll") for (int nt = 0; nt < 2; nt++) \
  _Pragma("unroll") for (int kk = 0; kk < 2; kk++) \
    acc[QD][mt][nt] = __builtin_amdgcn_mfma_f32_16x16x32_bf16(FA[mt][kk], FB[nt][kk], acc[QD][mt][nt], 0, 0, 0); \
  __builtin_amdgcn_s_setprio(0); } while (0)

  stage_tile(0, 0);

  const int NT = K >> 6;
  short8 af[4][2], af2[4][2], bf[2][2], bf2[2][2];

  for (int t = 0; t < NT; t++) {
    const int cur = t & 1;
    const bool last = (t == NT - 1);

    WAITV(4);                                   // A0,B0(t) done; A1,B1(t) may be in flight
    __builtin_amdgcn_s_barrier();
    __builtin_amdgcn_sched_barrier(0);
    if (!last) stage_tile(t + 1, cur ^ 1);      // 8 loads; slots freed by this barrier

    // p0: (A0,B0)
    ldA(af, &Asm[cur][0][0]);
    ldB(bf, &Bsm[cur][0][0]);
    MMQ(0, af, bf);

    if (last) { WAITV(0); } else { WAITV(8); }  // A1,B1(t) done; t+1's 8 loads in flight
    __builtin_amdgcn_s_barrier();
    __builtin_amdgcn_sched_barrier(0);

    // p1..p3: barrier-free drift region
    ldB(bf2, &Bsm[cur][1][0]);
    MMQ(1, af, bf2);
    ldA(af2, &Asm[cur][1][0]);
    MMQ(2, af2, bf);
    MMQ(3, af2, bf2);
  }
#undef MMQ

  // ---- epilogue: gelu(bf16) ----
#pragma unroll
  for (int qd = 0; qd < 4; qd++) {
    const int ha = qd >> 1, hb = qd & 1;
#pragma unroll
    for (int mt = 0; mt < 4; mt++) {
#pragma unroll
      for (int nt = 0; nt < 2; nt++) {
        f32x4 a = acc[qd][mt][nt];
        size_t col = (size_t)wcol0 + hb * 128 + (w & 3) * 32 + nt * 16 + m16;
        float bvv = bias[col];
        size_t rowb = (size_t)arow0 + ha * 128 + (w >> 2) * 64 + mt * 16 + quad * 4;
#pragma unroll
        for (int r = 0; r < 4; r++)
          Cb[(rowb + r) * (size_t)N + col] = f2bf(gelu_f(a[r] + bvv));
      }
    }
  }
}

// ---------------- flash attention: dual-Ps (per-qh buffer) ----------------
#define PSTR 72
__global__ void __launch_bounds__(256, 3) attn_kernel(const u16* __restrict__ qkv,
                                                      const u16* __restrict__ vtb,
                                                      u16* __restrict__ obuf)
{
  __shared__ u16 Ks[2][64 * 64];        // 2 x 8192 B
  __shared__ u16 Vs[2][64 * 64];        // 2 x 8192 B
  __shared__ u16 Ps[4][2][16 * PSTR];   // 18432 B        total 50 KB -> 3 blocks/CU

  const int tid = threadIdx.x;
  const int lane = tid & 63, wave = tid >> 6;
  const int m16 = lane & 15, quad = lane >> 4;
  const int bh = blockIdx.x;
  const int b = bh >> 4, h = bh & 15;
  const int q0 = blockIdx.y * 128 + wave * 32;     // this wave: q0..q0+31

  const u16* base = qkv + ((size_t)b * KTOK) * (3 * D_) + h * DH_;
  const u16* vb   = vtb + (size_t)bh * 64 * KTOK;  // rows = dh, stride KTOK

  short8 qf[2][2];
#pragma unroll
  for (int qh = 0; qh < 2; qh++) {
    const u16* qrow = base + (size_t)(q0 + qh * 16 + m16) * (3 * D_);
    qf[qh][0] = *(const short8*)(qrow + quad * 8);
    qf[qh][1] = *(const short8*)(qrow + 32 + quad * 8);
  }

  f32x4 oacc[2][4];
#pragma unroll
  for (int qh = 0; qh < 2; qh++)
#pragma unroll
    for (int nt = 0; nt < 4; nt++) oacc[qh][nt] = (f32x4)0.0f;
  f32x4 lsum[2] = {(f32x4)0.0f, (f32x4)0.0f};

  auto stage_tile = [&](const u16* g0, size_t rstride, u16* lds) {
#pragma unroll
    for (int c = 0; c < 2; c++) {
      int g = c * 256 + tid;
      int key = g >> 3;
      int cc = (g ^ key) & 7;
      gld_lds16(g0 + (size_t)key * rstride + cc * 8,
                lds + (size_t)(c * 256 + (tid & ~63)) * 8);
    }
  };

  stage_tile(base + D_, 3 * D_, &Ks[0][0]);
  stage_tile(vb, KTOK, &Vs[0][0]);
  __syncthreads();

  int buf = 0;
  for (int tk = 0; tk < KTOK; tk += 64) {
    if (tk + 64 < KTOK) {
      stage_tile(base + (size_t)(tk + 64) * (3 * D_) + D_, 3 * D_, &Ks[buf ^ 1][0]);
      stage_tile(vb + (tk + 64), KTOK, &Vs[buf ^ 1][0]);
    }
    const u16* Kb = &Ks[buf][0];
    const u16* Vb = &Vs[buf][0];

    // ---- S^T = K Q^T ----
    f32x4 sacc[2][4];
#pragma unroll
    for (int qh = 0; qh < 2; qh++)
#pragma unroll
      for (int nt = 0; nt < 4; nt++) sacc[qh][nt] = (f32x4)0.0f;
    __builtin_amdgcn_s_setprio(1);
#pragma unroll
    for (int nt = 0; nt < 4; nt++) {
      int row = nt * 16 + m16;
      int sw = row & 7;
      short8 kf0 = *(const short8*)&Kb[row * 64 + ((quad ^ sw) * 8)];
      short8 kf1 = *(const short8*)&Kb[row * 64 + (((4 + quad) ^ sw) * 8)];
#pragma unroll
      for (int qh = 0; qh < 2; qh++) {
        sacc[qh][nt] = __builtin_amdgcn_mfma_f32_16x16x32_bf16(kf0, qf[qh][0], sacc[qh][nt], 0, 0, 0);
        sacc[qh][nt] = __builtin_amdgcn_mfma_f32_16x16x32_bf16(kf1, qf[qh][1], sacc[qh][nt], 0, 0, 0);
      }
    }
    __builtin_amdgcn_s_setprio(0);

    // ---- hoisted V B-fragments ----
    short8 vf[4][2];
#pragma unroll
    for (int nt = 0; nt < 4; nt++) {
      int row = nt * 16 + m16;
      int sw = row & 7;
      vf[nt][0] = *(const short8*)&Vb[row * 64 + ((quad ^ sw) * 8)];
      vf[nt][1] = *(const short8*)&Vb[row * 64 + (((4 + quad) ^ sw) * 8)];
    }

    // ---- exp2 + pack + store BOTH qh (independent buffers -> no LDS aliasing hazard) ----
#pragma unroll
    for (int qh = 0; qh < 2; qh++) {
#pragma unroll
      for (int nt = 0; nt < 4; nt++) {
        f32x4 p;
#pragma unroll
        for (int r = 0; r < 4; r++) p[r] = EXP2F(sacc[qh][nt][r]);
        lsum[qh] += p;
        u32x2 w2; w2[0] = pkbf_t(p[0], p[1]); w2[1] = pkbf_t(p[2], p[3]);
        *(u32x2*)&Ps[wave][qh][m16 * PSTR + nt * 16 + quad * 4] = w2;
      }
    }
    // ---- read P A-frags for both qh, then one 16-MFMA PV cluster ----
    short8 pa[2][2];
#pragma unroll
    for (int qh = 0; qh < 2; qh++) {
      pa[qh][0] = *(const short8*)&Ps[wave][qh][m16 * PSTR + quad * 8];
      pa[qh][1] = *(const short8*)&Ps[wave][qh][m16 * PSTR + 32 + quad * 8];
    }
    __builtin_amdgcn_s_setprio(1);
#pragma unroll
    for (int qh = 0; qh < 2; qh++)
#pragma unroll
      for (int nt = 0; nt < 4; nt++) {
        oacc[qh][nt] = __builtin_amdgcn_mfma_f32_16x16x32_bf16(pa[qh][0], vf[nt][0], oacc[qh][nt], 0, 0, 0);
        oacc[qh][nt] = __builtin_amdgcn_mfma_f32_16x16x32_bf16(pa[qh][1], vf[nt][1], oacc[qh][nt], 0, 0, 0);
      }
    __builtin_amdgcn_s_setprio(0);

    __syncthreads();
    buf ^= 1;
  }

  float rl[2][4];
#pragma unroll
  for (int qh = 0; qh < 2; qh++) {
    float l = (lsum[qh][0] + lsum[qh][1]) + (lsum[qh][2] + lsum[qh][3]);
    l += __shfl_xor(l, 16);
    l += __shfl_xor(l, 32);
#pragma unroll
    for (int r = 0; r < 4; r++) {
      float lr = __shfl(l, (lane & 48) | (quad * 4 + r));
      rl[qh][r] = 1.0f / lr;
    }
  }

#pragma unroll
  for (int qh = 0; qh < 2; qh++)
#pragma unroll
    for (int nt = 0; nt < 4; nt++)
#pragma unroll
      for (int r = 0; r < 4; r++) {
        int qq = q0 + qh * 16 + quad * 4 + r;
        float v = oacc[qh][nt][r] * rl[qh][r];
        obuf[((size_t)b * KTOK + qq) * D_ + h * DH_ + nt * 16 + m16] = f2bf(v);
      }
}

// ---------------- launch ----------------
extern "C" void kernel_launch(void* const* d_in, const int* in_sizes, int n_in,
                              void* d_out, int out_size, void* d_ws, size_t ws_size,
                              hipStream_t stream)
{
  (void)in_sizes; (void)n_in; (void)out_size; (void)ws_size;
  const float* x          = (const float*)d_in[0];
  const float* w_router   = (const float*)d_in[1];
  const float* in_proj_w  = (const float*)d_in[2];
  const float* in_proj_b  = (const float*)d_in[3];
  const float* out_proj_w = (const float*)d_in[4];
  const float* out_proj_b = (const float*)d_in[5];
  const float* w1         = (const float*)d_in[6];
  const float* b1         = (const float*)d_in[7];
  const float* w2         = (const float*)d_in[8];
  const float* b2         = (const float*)d_in[9];
  const float* ln1g       = (const float*)d_in[10];
  const float* ln1b       = (const float*)d_in[11];
  const float* ln2g       = (const float*)d_in[12];
  const float* ln2b       = (const float*)d_in[13];
  float* out = (float*)d_out;

  char* w = (char*)d_ws;
  auto alloc = [&](size_t bytes) -> char* {
    char* p = w; w += (bytes + 255) & ~(size_t)255; return p;
  };
  float* logits = (float*)alloc((size_t)B_ * T_ * 4);
  int*   rnk    = (int*)  alloc((size_t)B_ * T_ * 4);
  int*   idx    = (int*)  alloc((size_t)B_ * KTOK * 4);
  float* auxacc = (float*)alloc(256);
  u16* inpw  = (u16*)alloc((size_t)3 * D_ * D_ * 2);
  u16* outpw = (u16*)alloc((size_t)D_ * D_ * 2);
  u16* w1b   = (u16*)alloc((size_t)4 * D_ * D_ * 2);
  u16* w2b   = (u16*)alloc((size_t)4 * D_ * D_ * 2);
  float* xs  = (float*)alloc((size_t)MROWS * D_ * 4);
  u16* hbuf  = (u16*)alloc((size_t)MROWS * D_ * 2);
  char* region = alloc((size_t)MROWS * 4 * D_ * 2);      // 64 MB: qkv(48)+obuf(16), reused by ff
  u16* qkvb = (u16*)region;
  u16* obuf = (u16*)(region + (size_t)MROWS * 3 * D_ * 2);
  u16* ffb  = (u16*)region;
  u16* vtb  = (u16*)alloc((size_t)B_ * H_ * DH_ * KTOK * 2);   // 16 MB: V transposed [bh][dh][tok]

  (void)hipMemsetAsync(auxacc, 0, 4, stream);
  (void)hipMemsetAsync(rnk, 0, (size_t)B_ * T_ * 4, stream);

  router_kernel<<<B_ * T_ / 4, 256, 0, stream>>>(x, w_router, logits, auxacc);
  rankp_kernel<<<dim3(T_ / 256, B_, 16), 256, 0, stream>>>(logits, rnk);
  lnpass_kernel<<<B_ * T_, 256, 0, stream>>>(x, rnk, ln1g, ln1b, xs, hbuf, out,
                                             idx, auxacc, out + (size_t)B_ * T_ * D_);

  f2bf_all<<<12 * D_ * D_ / 1024, 256, 0, stream>>>(in_proj_w, out_proj_w, w1, w2,
                                                    inpw, outpw, w1b, w2b);

  gemm_bt<0><<<dim3(3 * D_ / 128, MROWS / 128), 256, 0, stream>>>(
      hbuf, inpw, in_proj_b, nullptr, qkvb, nullptr, nullptr, vtb, MROWS, 3 * D_, D_);
  attn_kernel<<<dim3(B_ * H_, KTOK / 128), 256, 0, stream>>>(qkvb, vtb, obuf);
  gemm_bt<1><<<dim3(D_ / 128, MROWS / 128), 256, 0, stream>>>(
      obuf, outpw, out_proj_b, xs, nullptr, nullptr, nullptr, nullptr, MROWS, D_, D_);
  ln2_kernel<<<MROWS, 256, 0, stream>>>(xs, ln2g, ln2b, hbuf);
  gemm_ff1<<<dim3(4 * D_ / 256, MROWS / 256), 512, 0, stream>>>(
      hbuf, w1b, b1, ffb, MROWS, 4 * D_, D_);
  gemm_bt<3><<<dim3(D_ / 128, MROWS / 128), 256, 0, stream>>>(
      ffb, w2b, b2, xs, nullptr, out, idx, nullptr, MROWS, D_, 4 * D_);
}